// Round 1
// baseline (2735.154 us; speedup 1.0000x reference)
//
#include <hip/hip_runtime.h>
#include <stdint.h>

#define TOK 147456   // 16*96*96
#define CCH 512

typedef __attribute__((ext_vector_type(8))) short short8;
typedef __attribute__((ext_vector_type(4))) float f32x4;

struct alignas(8) US4 { unsigned short a, b, c, d; };

typedef __attribute__((address_space(3))) void lds_void;
typedef const __attribute__((address_space(1))) void gbl_void;

__device__ inline void gload16(const void* g, void* l) {
    __builtin_amdgcn_global_load_lds((gbl_void*)g, (lds_void*)l, 16, 0, 0);
}

__device__ inline unsigned short f2bf(float f) {
    union { float f; unsigned u; } v{f};
    unsigned r = v.u + 0x7fffu + ((v.u >> 16) & 1u);
    return (unsigned short)(r >> 16);
}
__device__ inline float bf2f(unsigned short h) {
    union { unsigned u; float f; } v; v.u = ((unsigned)h) << 16; return v.f;
}

// ---------------- weight transpose + cast:  in (K x N) f32 -> out (N x K) bf16
__global__ void wprep(const float* __restrict__ in, unsigned short* __restrict__ out,
                      int K, int N) {
    int idx = blockIdx.x * 256 + threadIdx.x;
    if (idx >= K * N) return;
    int k = idx / N, n = idx % N;              // coalesced read
    out[(size_t)n * K + k] = f2bf(in[idx]);
}

// ---------------- LayerNorm over C=512, one wave per token, out bf16
__global__ __launch_bounds__(256) void ln_k(const float* __restrict__ x,
                                            const float* __restrict__ g,
                                            const float* __restrict__ b,
                                            unsigned short* __restrict__ out, int ntok) {
    int lane = threadIdx.x & 63;
    int tok = blockIdx.x * 4 + (threadIdx.x >> 6);
    if (tok >= ntok) return;
    const float4* xr = (const float4*)(x + (size_t)tok * CCH);
    float4 v0 = xr[lane], v1 = xr[lane + 64];
    float s  = v0.x + v0.y + v0.z + v0.w + v1.x + v1.y + v1.z + v1.w;
    float s2 = v0.x*v0.x + v0.y*v0.y + v0.z*v0.z + v0.w*v0.w
             + v1.x*v1.x + v1.y*v1.y + v1.z*v1.z + v1.w*v1.w;
#pragma unroll
    for (int off = 32; off; off >>= 1) { s += __shfl_xor(s, off); s2 += __shfl_xor(s2, off); }
    float mean = s * (1.f / 512.f);
    float var  = s2 * (1.f / 512.f) - mean * mean;
    float inv  = rsqrtf(var + 1e-5f);
    const float4* gp = (const float4*)g;
    const float4* bp = (const float4*)b;
    float4 g0 = gp[lane], g1 = gp[lane + 64], b0 = bp[lane], b1 = bp[lane + 64];
    US4 o0, o1;
    o0.a = f2bf((v0.x - mean) * inv * g0.x + b0.x);
    o0.b = f2bf((v0.y - mean) * inv * g0.y + b0.y);
    o0.c = f2bf((v0.z - mean) * inv * g0.z + b0.z);
    o0.d = f2bf((v0.w - mean) * inv * g0.w + b0.w);
    o1.a = f2bf((v1.x - mean) * inv * g1.x + b1.x);
    o1.b = f2bf((v1.y - mean) * inv * g1.y + b1.y);
    o1.c = f2bf((v1.z - mean) * inv * g1.z + b1.z);
    o1.d = f2bf((v1.w - mean) * inv * g1.w + b1.w);
    unsigned short* op = out + (size_t)tok * CCH;
    *(US4*)(op + 4 * lane)       = o0;
    *(US4*)(op + 256 + 4 * lane) = o1;
}

// ---------------- windowed attention, one wave per (window, head)
// qkv: ntok x 1536 bf16 (local raster order), o: ntok x 512 bf16
__global__ __launch_bounds__(64) void attn_k(const unsigned short* __restrict__ qkv,
                                             const float* __restrict__ rel_bias,
                                             unsigned short* __restrict__ o) {
    __shared__ float qs[36][32], ks[36][32], vs[36][32], S[36][36];
    int h = blockIdx.x & 15;
    int w = blockIdx.x >> 4;          // local window id
    int b    = w >> 8;                // local image
    int wrow = (w >> 4) & 15;
    int wcol = w & 15;
    int tid = threadIdx.x;
    int tok_base = (b * 96 + wrow * 6) * 96 + wcol * 6;

    for (int e = tid; e < 36 * 32; e += 64) {
        int n = e >> 5, d0 = e & 31;
        int row = tok_base + (n / 6) * 96 + (n % 6);
        size_t base = (size_t)row * 1536 + h * 32 + d0;
        qs[n][d0] = bf2f(qkv[base]) * 0.17677669529663687f;  // 1/sqrt(32)
        ks[n][d0] = bf2f(qkv[base + 512]);
        vs[n][d0] = bf2f(qkv[base + 1024]);
    }
    __syncthreads();
    for (int e = tid; e < 36 * 36; e += 64) {
        int n = e / 36, m = e % 36;
        float acc = 0.f;
#pragma unroll
        for (int kk = 0; kk < 32; ++kk) acc += qs[n][kk] * ks[m][kk];
        int dy = (n / 6) - (m / 6) + 5;
        int dx = (n % 6) - (m % 6) + 5;
        acc += rel_bias[(dy * 11 + dx) * 16 + h];
        S[n][m] = acc;
    }
    __syncthreads();
    if (tid < 36) {
        float mx = -1e30f;
#pragma unroll
        for (int m = 0; m < 36; ++m) mx = fmaxf(mx, S[tid][m]);
        float sum = 0.f;
#pragma unroll
        for (int m = 0; m < 36; ++m) { float e = __expf(S[tid][m] - mx); S[tid][m] = e; sum += e; }
        float inv = 1.f / sum;
#pragma unroll
        for (int m = 0; m < 36; ++m) S[tid][m] *= inv;
    }
    __syncthreads();
    for (int e = tid; e < 36 * 32; e += 64) {
        int n = e >> 5, d0 = e & 31;
        float acc = 0.f;
#pragma unroll
        for (int m = 0; m < 36; ++m) acc += S[n][m] * vs[m][d0];
        int row = tok_base + (n / 6) * 96 + (n % 6);
        o[(size_t)row * CCH + h * 32 + d0] = f2bf(acc);
    }
}

// ---------------- bf16 MFMA GEMM, C = A (MxK) * Bt^T (Bt is NxK), 128x128 tile
// EPI: 0 = bf16 store (no bias); 1 = f32 store + bias; 2 = bf16 gelu(x+bias);
//      3 = f32 store (x+bias+resid)
template <int EPI>
__global__ __launch_bounds__(256) void gemm_bt(const unsigned short* __restrict__ A,
                                               const unsigned short* __restrict__ Bt,
                                               int M, int N, int K,
                                               const float* __restrict__ bias,
                                               const float* __restrict__ resid,
                                               void* __restrict__ Cout) {
    __shared__ unsigned short Alds[128 * 32];
    __shared__ unsigned short Blds[128 * 32];
    int tid = threadIdx.x;
    int nbn = N >> 7;
    int bm = blockIdx.x / nbn, bn = blockIdx.x % nbn;

    const unsigned short* ap = A  + (size_t)bm * 128 * K + (size_t)(tid >> 2) * K + (tid & 3) * 8;
    const unsigned short* bp = Bt + (size_t)bn * 128 * K + (size_t)(tid >> 2) * K + (tid & 3) * 8;
    unsigned short* al = Alds + tid * 8;
    unsigned short* bl = Blds + tid * 8;

    int lane = tid & 63;
    int wv = tid >> 6, wr = wv >> 1, wc = wv & 1;
    int arow = wr * 64 + (lane & 15);
    int brow = wc * 64 + (lane & 15);
    int kg = (lane >> 4) * 8;

    f32x4 acc[4][4] = {};

    for (int kt = 0; kt < K; kt += 32) {
        gload16(ap + kt, al);
        gload16(ap + kt + (size_t)64 * K, al + 2048);
        gload16(bp + kt, bl);
        gload16(bp + kt + (size_t)64 * K, bl + 2048);
        asm volatile("s_waitcnt vmcnt(0)" ::: "memory");
        __syncthreads();
        short8 af[4], bf[4];
#pragma unroll
        for (int m = 0; m < 4; ++m) af[m] = *(const short8*)(Alds + (arow + m * 16) * 32 + kg);
#pragma unroll
        for (int n = 0; n < 4; ++n) bf[n] = *(const short8*)(Blds + (brow + n * 16) * 32 + kg);
#pragma unroll
        for (int m = 0; m < 4; ++m)
#pragma unroll
            for (int n = 0; n < 4; ++n)
                acc[m][n] = __builtin_amdgcn_mfma_f32_16x16x32_bf16(af[m], bf[n], acc[m][n], 0, 0, 0);
        __syncthreads();
    }

    int row0 = bm * 128 + wr * 64 + (lane >> 4) * 4;
    int col0 = bn * 128 + wc * 64 + (lane & 15);
#pragma unroll
    for (int m = 0; m < 4; ++m) {
#pragma unroll
        for (int n = 0; n < 4; ++n) {
            int col = col0 + n * 16;
            float bv = (EPI == 0) ? 0.f : bias[col];
#pragma unroll
            for (int r = 0; r < 4; ++r) {
                int row = row0 + m * 16 + r;
                size_t idx = (size_t)row * N + col;
                float val = acc[m][n][r] + bv;
                if (EPI == 0) {
                    ((unsigned short*)Cout)[idx] = f2bf(val);
                } else if (EPI == 1) {
                    ((float*)Cout)[idx] = val;
                } else if (EPI == 2) {
                    float ge = 0.5f * val * (1.f + erff(val * 0.70710678118654752f));
                    ((unsigned short*)Cout)[idx] = f2bf(ge);
                } else {
                    ((float*)Cout)[idx] = val + resid[idx];
                }
            }
        }
    }
}

extern "C" void kernel_launch(void* const* d_in, const int* in_sizes, int n_in,
                              void* d_out, int out_size, void* d_ws, size_t ws_size,
                              hipStream_t stream) {
    const float* x       = (const float*)d_in[0];
    const float* w_qkv   = (const float*)d_in[1];
    const float* w_proj  = (const float*)d_in[2];
    const float* b_proj  = (const float*)d_in[3];
    const float* relb    = (const float*)d_in[4];
    const float* ln1g    = (const float*)d_in[5];
    const float* ln1b    = (const float*)d_in[6];
    const float* ln2g    = (const float*)d_in[7];
    const float* ln2b    = (const float*)d_in[8];
    const float* w_fc1   = (const float*)d_in[9];
    const float* b_fc1   = (const float*)d_in[10];
    const float* w_fc2   = (const float*)d_in[11];
    const float* b_fc2   = (const float*)d_in[12];
    float* out = (float*)d_out;

    char* w = (char*)d_ws;
    unsigned short* wT_qkv  = (unsigned short*)w; w += (size_t)1536 * 512 * 2;
    unsigned short* wT_proj = (unsigned short*)w; w += (size_t)512  * 512 * 2;
    unsigned short* wT_fc1  = (unsigned short*)w; w += (size_t)2048 * 512 * 2;
    unsigned short* wT_fc2  = (unsigned short*)w; w += (size_t)512  * 2048 * 2;
    size_t wbytes = (size_t)(w - (char*)d_ws);

    // pick batch-chunking so activation buffers fit ws
    int nchunk = 16;
    for (int c = 1; c <= 16; c *= 2) {
        size_t tokc = TOK / c;
        if (wbytes + tokc * 1024 + tokc * 4096 <= ws_size) { nchunk = c; break; }
    }
    size_t tokc = TOK / nchunk;
    unsigned short* buf1 = (unsigned short*)w;               // tokc x 512  bf16
    unsigned short* buf2 = (unsigned short*)(w + tokc * 1024); // tokc x 2048 bf16

    wprep<<<(512 * 1536 + 255) / 256, 256, 0, stream>>>(w_qkv,  wT_qkv,  512, 1536);
    wprep<<<(512 * 512  + 255) / 256, 256, 0, stream>>>(w_proj, wT_proj, 512, 512);
    wprep<<<(512 * 2048 + 255) / 256, 256, 0, stream>>>(w_fc1,  wT_fc1,  512, 2048);
    wprep<<<(2048 * 512 + 255) / 256, 256, 0, stream>>>(w_fc2,  wT_fc2,  2048, 512);

    int Mc = (int)tokc;            // tokens per chunk (multiple of 9216)
    int gm = Mc / 128;
    int nwin_blocks = (Mc / 9216) * 4096;  // images_per_chunk * 256 windows * 16 heads

    for (int c = 0; c < nchunk; ++c) {
        size_t toff = (size_t)c * tokc;
        const float* xc = x + toff * CCH;
        float* outc = out + toff * CCH;

        ln_k<<<Mc / 4, 256, 0, stream>>>(xc, ln1g, ln1b, buf1, Mc);
        gemm_bt<0><<<gm * 12, 256, 0, stream>>>(buf1, wT_qkv, Mc, 1536, 512,
                                                nullptr, nullptr, buf2);
        attn_k<<<nwin_blocks, 64, 0, stream>>>(buf2, relb, buf1);
        gemm_bt<1><<<gm * 4, 256, 0, stream>>>(buf1, wT_proj, Mc, 512, 512,
                                               b_proj, nullptr, outc);
        ln_k<<<Mc / 4, 256, 0, stream>>>(outc, ln2g, ln2b, buf1, Mc);
        gemm_bt<2><<<gm * 16, 256, 0, stream>>>(buf1, wT_fc1, Mc, 2048, 512,
                                                b_fc1, nullptr, buf2);
        gemm_bt<3><<<gm * 4, 256, 0, stream>>>(buf2, wT_fc2, Mc, 512, 2048,
                                               b_fc2, outc, outc);
    }
}

// Round 2
// 2102.976 us; speedup vs baseline: 1.3006x; 1.3006x over previous
//
#include <hip/hip_runtime.h>
#include <stdint.h>

#define TOK 147456   // 16*96*96
#define CCH 512

typedef __attribute__((ext_vector_type(8))) short short8;
typedef __attribute__((ext_vector_type(4))) float f32x4;
typedef unsigned short ushort_t;

struct alignas(8) US4 { unsigned short a, b, c, d; };

typedef __attribute__((address_space(3))) void lds_void;
typedef const __attribute__((address_space(1))) void gbl_void;

__device__ inline void gload16(const void* g, void* l) {
    __builtin_amdgcn_global_load_lds((gbl_void*)g, (lds_void*)l, 16, 0, 0);
}

__device__ inline unsigned short f2bf(float f) {
    union { float f; unsigned u; } v{f};
    unsigned r = v.u + 0x7fffu + ((v.u >> 16) & 1u);
    return (unsigned short)(r >> 16);
}
__device__ inline float bf2f(unsigned short h) {
    union { unsigned u; float f; } v; v.u = ((unsigned)h) << 16; return v.f;
}

// ---------------- weight transpose + cast:  in (K x N) f32 -> out (N x K) bf16
__global__ void wprep(const float* __restrict__ in, unsigned short* __restrict__ out,
                      int K, int N) {
    int idx = blockIdx.x * 256 + threadIdx.x;
    if (idx >= K * N) return;
    int k = idx / N, n = idx % N;              // coalesced read
    out[(size_t)n * K + k] = f2bf(in[idx]);
}

// ---------------- rel_bias -> dense (16,48,48) f32 table, padded with -1e9
__global__ void biasprep(const float* __restrict__ rb, float* __restrict__ bb) {
    int idx = blockIdx.x * 256 + threadIdx.x;
    if (idx >= 16 * 48 * 48) return;
    int h = idx / 2304, rem = idx % 2304, r = rem / 48, c = rem % 48;
    float v = -1e9f;
    if (r < 36 && c < 36) {
        int dy = r / 6 - c / 6 + 5;
        int dx = r % 6 - c % 6 + 5;
        v = rb[(dy * 11 + dx) * 16 + h];
    }
    bb[idx] = v;
}

// ---------------- LayerNorm over C=512, one wave per token, out bf16
__global__ __launch_bounds__(256) void ln_k(const float* __restrict__ x,
                                            const float* __restrict__ g,
                                            const float* __restrict__ b,
                                            unsigned short* __restrict__ out, int ntok) {
    int lane = threadIdx.x & 63;
    int tok = blockIdx.x * 4 + (threadIdx.x >> 6);
    if (tok >= ntok) return;
    const float4* xr = (const float4*)(x + (size_t)tok * CCH);
    float4 v0 = xr[lane], v1 = xr[lane + 64];
    float s  = v0.x + v0.y + v0.z + v0.w + v1.x + v1.y + v1.z + v1.w;
    float s2 = v0.x*v0.x + v0.y*v0.y + v0.z*v0.z + v0.w*v0.w
             + v1.x*v1.x + v1.y*v1.y + v1.z*v1.z + v1.w*v1.w;
#pragma unroll
    for (int off = 32; off; off >>= 1) { s += __shfl_xor(s, off); s2 += __shfl_xor(s2, off); }
    float mean = s * (1.f / 512.f);
    float var  = s2 * (1.f / 512.f) - mean * mean;
    float inv  = rsqrtf(var + 1e-5f);
    const float4* gp = (const float4*)g;
    const float4* bp = (const float4*)b;
    float4 g0 = gp[lane], g1 = gp[lane + 64], b0 = bp[lane], b1 = bp[lane + 64];
    US4 o0, o1;
    o0.a = f2bf((v0.x - mean) * inv * g0.x + b0.x);
    o0.b = f2bf((v0.y - mean) * inv * g0.y + b0.y);
    o0.c = f2bf((v0.z - mean) * inv * g0.z + b0.z);
    o0.d = f2bf((v0.w - mean) * inv * g0.w + b0.w);
    o1.a = f2bf((v1.x - mean) * inv * g1.x + b1.x);
    o1.b = f2bf((v1.y - mean) * inv * g1.y + b1.y);
    o1.c = f2bf((v1.z - mean) * inv * g1.z + b1.z);
    o1.d = f2bf((v1.w - mean) * inv * g1.w + b1.w);
    unsigned short* op = out + (size_t)tok * CCH;
    *(US4*)(op + 4 * lane)       = o0;
    *(US4*)(op + 256 + 4 * lane) = o1;
}

// ---------------- MFMA windowed attention: one wave per (window, head)
// qkv: ntok x 1536 bf16, biasb: (16,48,48) f32 (pad=-1e9), o: ntok x 512 bf16
__global__ __launch_bounds__(256) void attn_mfma(const unsigned short* __restrict__ qkv,
                                                 const float* __restrict__ biasb,
                                                 unsigned short* __restrict__ o) {
    // per-wave LDS: P (48x64 bf16, XOR-swizzled), V^T (32x64 bf16, XOR-swizzled)
    __shared__ __align__(16) unsigned short p_lds[4][48 * 64];
    __shared__ __align__(16) unsigned short v_lds[4][32 * 64];

    int tid  = threadIdx.x;
    int wv   = tid >> 6;
    int lane = tid & 63;
    int l15  = lane & 15;
    int g    = lane >> 4;

    int wid = blockIdx.x * 4 + wv;
    int h   = wid & 15;
    int win = wid >> 4;
    int img  = win >> 8;
    int wrow = (win >> 4) & 15;
    int wcol = win & 15;
    int tok_base = (img * 96 + wrow * 6) * 96 + wcol * 6;

    unsigned short* pw = p_lds[wv];
    unsigned short* vw = v_lds[wv];

    // token index for window-local row r (r < 36)
    #define TOKOF(r) (tok_base + (r) + 90 * ((r) / 6))

    // ---- zero the padded K-region of both LDS tiles (no 0*garbage NaNs)
    short8 z8 = {};
    for (int e = lane; e < 224; e += 64) {
        if (e < 128) {
            int ch = e >> 2, kst = 32 + (e & 3) * 8;
            *(short8*)(vw + ch * 64 + (kst ^ ((ch & 7) << 3))) = z8;
        } else {
            int ee = e - 128; int q = ee >> 1, kst = 48 + (ee & 1) * 8;
            *(short8*)(pw + q * 64 + (kst ^ ((q & 7) << 3))) = z8;
        }
    }

    // ---- stage V^T into LDS (transposed, swizzled)
    for (int e = lane; e < 144; e += 64) {
        int r = e >> 2, c0 = (e & 3) * 8;
        short8 vv = *(const short8*)(qkv + (size_t)TOKOF(r) * 1536 + 1024 + h * 32 + c0);
#pragma unroll
        for (int j = 0; j < 8; ++j) {
            int ch = c0 + j;
            vw[ch * 64 + (r ^ ((ch & 7) << 3))] = (unsigned short)vv[j];
        }
    }

    // ---- Q/K fragments straight from global (A/B layout: row=lane&15, k=(lane>>4)*8)
    short8 qf[3], kf[3];
#pragma unroll
    for (int t = 0; t < 3; ++t) {
        int r = t * 16 + l15;
        if (r < 36) {
            size_t ba = (size_t)TOKOF(r) * 1536 + h * 32 + g * 8;
            qf[t] = *(const short8*)(qkv + ba);
            kf[t] = *(const short8*)(qkv + ba + 512);
        } else { qf[t] = z8; kf[t] = z8; }
    }

    // ---- S = Q K^T  (9 mfma, 48x48 padded)
    f32x4 s[3][3] = {};
#pragma unroll
    for (int mt = 0; mt < 3; ++mt)
#pragma unroll
        for (int nt = 0; nt < 3; ++nt)
            s[mt][nt] = __builtin_amdgcn_mfma_f32_16x16x32_bf16(qf[mt], kf[nt], s[mt][nt], 0, 0, 0);

    // ---- softmax (wave-parallel, rows owned by 16-lane groups), write P to LDS
    const float SCALE = 0.17677669529663687f;  // 1/sqrt(32)
    const float* bh = biasb + h * 2304;
#pragma unroll
    for (int mt = 0; mt < 3; ++mt) {
#pragma unroll
        for (int r = 0; r < 4; ++r) {
            int row = mt * 16 + g * 4 + r;
            const float* bb = bh + row * 48 + l15;
            float v0 = fmaf(s[mt][0][r], SCALE, bb[0]);
            float v1 = fmaf(s[mt][1][r], SCALE, bb[16]);
            float v2 = fmaf(s[mt][2][r], SCALE, bb[32]);
            float m = fmaxf(fmaxf(v0, v1), v2);
#pragma unroll
            for (int off = 1; off < 16; off <<= 1) m = fmaxf(m, __shfl_xor(m, off));
            float e0 = __expf(v0 - m), e1 = __expf(v1 - m), e2 = __expf(v2 - m);
            float sm = e0 + e1 + e2;
#pragma unroll
            for (int off = 1; off < 16; off <<= 1) sm += __shfl_xor(sm, off);
            float inv = 1.f / sm;
            int sw = (row & 7) << 3;
            unsigned short* pr = pw + row * 64;
            pr[(l15)      ^ sw] = f2bf(e0 * inv);
            pr[(16 + l15) ^ sw] = f2bf(e1 * inv);
            pr[(32 + l15) ^ sw] = f2bf(e2 * inv);
        }
    }

    // ---- O = P V  (12 mfma: 3 q-tiles x 2 c-tiles x 2 k-steps)
    f32x4 oacc[3][2] = {};
#pragma unroll
    for (int ks = 0; ks < 2; ++ks) {
        int kst = ks * 32 + g * 8;
        short8 bfr[2];
#pragma unroll
        for (int nt = 0; nt < 2; ++nt) {
            int c = nt * 16 + l15;
            bfr[nt] = *(const short8*)(vw + c * 64 + (kst ^ ((c & 7) << 3)));
        }
#pragma unroll
        for (int mt = 0; mt < 3; ++mt) {
            int q = mt * 16 + l15;
            short8 pa = *(const short8*)(pw + q * 64 + (kst ^ ((q & 7) << 3)));
#pragma unroll
            for (int nt = 0; nt < 2; ++nt)
                oacc[mt][nt] = __builtin_amdgcn_mfma_f32_16x16x32_bf16(pa, bfr[nt], oacc[mt][nt], 0, 0, 0);
        }
    }

    // ---- store O (rows < 36)
#pragma unroll
    for (int mt = 0; mt < 3; ++mt) {
#pragma unroll
        for (int r = 0; r < 4; ++r) {
            int q = mt * 16 + g * 4 + r;
            if (q < 36) {
                size_t rb = (size_t)TOKOF(q) * 512 + h * 32;
#pragma unroll
                for (int nt = 0; nt < 2; ++nt)
                    o[rb + nt * 16 + l15] = f2bf(oacc[mt][nt][r]);
            }
        }
    }
    #undef TOKOF
}

// ---------------- bf16 MFMA GEMM, C = A (MxK) * Bt^T (Bt is NxK), 128x128 tile
// EPI: 0 = bf16 store (no bias); 1 = f32 store + bias; 2 = bf16 gelu(x+bias);
//      3 = f32 store (x+bias+resid)
template <int EPI>
__global__ __launch_bounds__(256) void gemm_bt(const unsigned short* __restrict__ A,
                                               const unsigned short* __restrict__ Bt,
                                               int M, int N, int K,
                                               const float* __restrict__ bias,
                                               const float* __restrict__ resid,
                                               void* __restrict__ Cout) {
    __shared__ unsigned short Alds[128 * 32];
    __shared__ unsigned short Blds[128 * 32];
    int tid = threadIdx.x;
    int nbn = N >> 7;
    int bm = blockIdx.x / nbn, bn = blockIdx.x % nbn;

    const unsigned short* ap = A  + (size_t)bm * 128 * K + (size_t)(tid >> 2) * K + (tid & 3) * 8;
    const unsigned short* bp = Bt + (size_t)bn * 128 * K + (size_t)(tid >> 2) * K + (tid & 3) * 8;
    unsigned short* al = Alds + tid * 8;
    unsigned short* bl = Blds + tid * 8;

    int lane = tid & 63;
    int wv = tid >> 6, wr = wv >> 1, wc = wv & 1;
    int arow = wr * 64 + (lane & 15);
    int brow = wc * 64 + (lane & 15);
    int kg = (lane >> 4) * 8;

    f32x4 acc[4][4] = {};

    for (int kt = 0; kt < K; kt += 32) {
        gload16(ap + kt, al);
        gload16(ap + kt + (size_t)64 * K, al + 2048);
        gload16(bp + kt, bl);
        gload16(bp + kt + (size_t)64 * K, bl + 2048);
        asm volatile("s_waitcnt vmcnt(0)" ::: "memory");
        __syncthreads();
        short8 af[4], bf[4];
#pragma unroll
        for (int m = 0; m < 4; ++m) af[m] = *(const short8*)(Alds + (arow + m * 16) * 32 + kg);
#pragma unroll
        for (int n = 0; n < 4; ++n) bf[n] = *(const short8*)(Blds + (brow + n * 16) * 32 + kg);
#pragma unroll
        for (int m = 0; m < 4; ++m)
#pragma unroll
            for (int n = 0; n < 4; ++n)
                acc[m][n] = __builtin_amdgcn_mfma_f32_16x16x32_bf16(af[m], bf[n], acc[m][n], 0, 0, 0);
        __syncthreads();
    }

    int row0 = bm * 128 + wr * 64 + (lane >> 4) * 4;
    int col0 = bn * 128 + wc * 64 + (lane & 15);
#pragma unroll
    for (int m = 0; m < 4; ++m) {
#pragma unroll
        for (int n = 0; n < 4; ++n) {
            int col = col0 + n * 16;
            float bv = (EPI == 0) ? 0.f : bias[col];
#pragma unroll
            for (int r = 0; r < 4; ++r) {
                int row = row0 + m * 16 + r;
                size_t idx = (size_t)row * N + col;
                float val = acc[m][n][r] + bv;
                if (EPI == 0) {
                    ((unsigned short*)Cout)[idx] = f2bf(val);
                } else if (EPI == 1) {
                    ((float*)Cout)[idx] = val;
                } else if (EPI == 2) {
                    float ge = 0.5f * val * (1.f + erff(val * 0.70710678118654752f));
                    ((unsigned short*)Cout)[idx] = f2bf(ge);
                } else {
                    ((float*)Cout)[idx] = val + resid[idx];
                }
            }
        }
    }
}

extern "C" void kernel_launch(void* const* d_in, const int* in_sizes, int n_in,
                              void* d_out, int out_size, void* d_ws, size_t ws_size,
                              hipStream_t stream) {
    const float* x       = (const float*)d_in[0];
    const float* w_qkv   = (const float*)d_in[1];
    const float* w_proj  = (const float*)d_in[2];
    const float* b_proj  = (const float*)d_in[3];
    const float* relb    = (const float*)d_in[4];
    const float* ln1g    = (const float*)d_in[5];
    const float* ln1b    = (const float*)d_in[6];
    const float* ln2g    = (const float*)d_in[7];
    const float* ln2b    = (const float*)d_in[8];
    const float* w_fc1   = (const float*)d_in[9];
    const float* b_fc1   = (const float*)d_in[10];
    const float* w_fc2   = (const float*)d_in[11];
    const float* b_fc2   = (const float*)d_in[12];
    float* out = (float*)d_out;

    char* w = (char*)d_ws;
    unsigned short* wT_qkv  = (unsigned short*)w; w += (size_t)1536 * 512 * 2;
    unsigned short* wT_proj = (unsigned short*)w; w += (size_t)512  * 512 * 2;
    unsigned short* wT_fc1  = (unsigned short*)w; w += (size_t)2048 * 512 * 2;
    unsigned short* wT_fc2  = (unsigned short*)w; w += (size_t)512  * 2048 * 2;
    float* biasb            = (float*)w;          w += (size_t)16 * 48 * 48 * 4;
    size_t wbytes = (size_t)(w - (char*)d_ws);

    // pick batch-chunking so activation buffers fit ws
    int nchunk = 16;
    for (int c = 1; c <= 16; c *= 2) {
        size_t tokc = TOK / c;
        if (wbytes + tokc * 1024 + tokc * 4096 <= ws_size) { nchunk = c; break; }
    }
    size_t tokc = TOK / nchunk;
    unsigned short* buf1 = (unsigned short*)w;               // tokc x 512  bf16
    unsigned short* buf2 = (unsigned short*)(w + tokc * 1024); // tokc x 2048 bf16

    wprep<<<(512 * 1536 + 255) / 256, 256, 0, stream>>>(w_qkv,  wT_qkv,  512, 1536);
    wprep<<<(512 * 512  + 255) / 256, 256, 0, stream>>>(w_proj, wT_proj, 512, 512);
    wprep<<<(512 * 2048 + 255) / 256, 256, 0, stream>>>(w_fc1,  wT_fc1,  512, 2048);
    wprep<<<(2048 * 512 + 255) / 256, 256, 0, stream>>>(w_fc2,  wT_fc2,  2048, 512);
    biasprep<<<(16 * 48 * 48 + 255) / 256, 256, 0, stream>>>(relb, biasb);

    int Mc = (int)tokc;            // tokens per chunk (multiple of 9216)
    int gm = Mc / 128;
    int imgs = Mc / 9216;          // images per chunk

    for (int c = 0; c < nchunk; ++c) {
        size_t toff = (size_t)c * tokc;
        const float* xc = x + toff * CCH;
        float* outc = out + toff * CCH;

        ln_k<<<Mc / 4, 256, 0, stream>>>(xc, ln1g, ln1b, buf1, Mc);
        gemm_bt<0><<<gm * 12, 256, 0, stream>>>(buf1, wT_qkv, Mc, 1536, 512,
                                                nullptr, nullptr, buf2);
        attn_mfma<<<imgs * 1024, 256, 0, stream>>>(buf2, biasb, buf1);
        gemm_bt<1><<<gm * 4, 256, 0, stream>>>(buf1, wT_proj, Mc, 512, 512,
                                               b_proj, nullptr, outc);
        ln_k<<<Mc / 4, 256, 0, stream>>>(outc, ln2g, ln2b, buf1, Mc);
        gemm_bt<2><<<gm * 16, 256, 0, stream>>>(buf1, wT_fc1, Mc, 2048, 512,
                                                b_fc1, nullptr, buf2);
        gemm_bt<3><<<gm * 4, 256, 0, stream>>>(buf2, wT_fc2, Mc, 512, 2048,
                                               b_fc2, outc, outc);
    }
}

// Round 3
// 1867.451 us; speedup vs baseline: 1.4646x; 1.1261x over previous
//
#include <hip/hip_runtime.h>
#include <stdint.h>

#define TOK 147456   // 16*96*96
#define CCH 512

typedef __attribute__((ext_vector_type(8))) short short8;
typedef __attribute__((ext_vector_type(4))) float f32x4;

struct alignas(8) US4 { unsigned short a, b, c, d; };

typedef __attribute__((address_space(3))) void lds_void;
typedef const __attribute__((address_space(1))) void gbl_void;

__device__ inline void gload16(const void* g, void* l) {
    __builtin_amdgcn_global_load_lds((gbl_void*)g, (lds_void*)l, 16, 0, 0);
}

__device__ inline unsigned short f2bf(float f) {
    union { float f; unsigned u; } v{f};
    unsigned r = v.u + 0x7fffu + ((v.u >> 16) & 1u);
    return (unsigned short)(r >> 16);
}
__device__ inline float bf2f(unsigned short h) {
    union { unsigned u; float f; } v; v.u = ((unsigned)h) << 16; return v.f;
}

// ---------------- weight transpose + cast:  in (K x N) f32 -> out (N x K) bf16
__global__ void wprep(const float* __restrict__ in, unsigned short* __restrict__ out,
                      int K, int N) {
    int idx = blockIdx.x * 256 + threadIdx.x;
    if (idx >= K * N) return;
    int k = idx / N, n = idx % N;              // coalesced read
    out[(size_t)n * K + k] = f2bf(in[idx]);
}

// ---------------- rel_bias -> dense (16,48,48) f32 table, padded with -1e9
__global__ void biasprep(const float* __restrict__ rb, float* __restrict__ bb) {
    int idx = blockIdx.x * 256 + threadIdx.x;
    if (idx >= 16 * 48 * 48) return;
    int h = idx / 2304, rem = idx % 2304, r = rem / 48, c = rem % 48;
    float v = -1e9f;
    if (r < 36 && c < 36) {
        int dy = r / 6 - c / 6 + 5;
        int dx = r % 6 - c % 6 + 5;
        v = rb[(dy * 11 + dx) * 16 + h];
    }
    bb[idx] = v;
}

// ---------------- LayerNorm over C=512, one wave per token, out bf16
__global__ __launch_bounds__(256) void ln_k(const float* __restrict__ x,
                                            const float* __restrict__ g,
                                            const float* __restrict__ b,
                                            unsigned short* __restrict__ out, int ntok) {
    int lane = threadIdx.x & 63;
    int tok = blockIdx.x * 4 + (threadIdx.x >> 6);
    if (tok >= ntok) return;
    const float4* xr = (const float4*)(x + (size_t)tok * CCH);
    float4 v0 = xr[lane], v1 = xr[lane + 64];
    float s  = v0.x + v0.y + v0.z + v0.w + v1.x + v1.y + v1.z + v1.w;
    float s2 = v0.x*v0.x + v0.y*v0.y + v0.z*v0.z + v0.w*v0.w
             + v1.x*v1.x + v1.y*v1.y + v1.z*v1.z + v1.w*v1.w;
#pragma unroll
    for (int off = 32; off; off >>= 1) { s += __shfl_xor(s, off); s2 += __shfl_xor(s2, off); }
    float mean = s * (1.f / 512.f);
    float var  = s2 * (1.f / 512.f) - mean * mean;
    float inv  = rsqrtf(var + 1e-5f);
    const float4* gp = (const float4*)g;
    const float4* bp = (const float4*)b;
    float4 g0 = gp[lane], g1 = gp[lane + 64], b0 = bp[lane], b1 = bp[lane + 64];
    US4 o0, o1;
    o0.a = f2bf((v0.x - mean) * inv * g0.x + b0.x);
    o0.b = f2bf((v0.y - mean) * inv * g0.y + b0.y);
    o0.c = f2bf((v0.z - mean) * inv * g0.z + b0.z);
    o0.d = f2bf((v0.w - mean) * inv * g0.w + b0.w);
    o1.a = f2bf((v1.x - mean) * inv * g1.x + b1.x);
    o1.b = f2bf((v1.y - mean) * inv * g1.y + b1.y);
    o1.c = f2bf((v1.z - mean) * inv * g1.z + b1.z);
    o1.d = f2bf((v1.w - mean) * inv * g1.w + b1.w);
    unsigned short* op = out + (size_t)tok * CCH;
    *(US4*)(op + 4 * lane)       = o0;
    *(US4*)(op + 256 + 4 * lane) = o1;
}

// ---------------- MFMA windowed attention: one wave per (window, head)
__global__ __launch_bounds__(256) void attn_mfma(const unsigned short* __restrict__ qkv,
                                                 const float* __restrict__ biasb,
                                                 unsigned short* __restrict__ o) {
    __shared__ __align__(16) unsigned short p_lds[4][48 * 64];
    __shared__ __align__(16) unsigned short v_lds[4][32 * 64];

    int tid  = threadIdx.x;
    int wv   = tid >> 6;
    int lane = tid & 63;
    int l15  = lane & 15;
    int g    = lane >> 4;

    int wid = blockIdx.x * 4 + wv;
    int h   = wid & 15;
    int win = wid >> 4;
    int img  = win >> 8;
    int wrow = (win >> 4) & 15;
    int wcol = win & 15;
    int tok_base = (img * 96 + wrow * 6) * 96 + wcol * 6;

    unsigned short* pw = p_lds[wv];
    unsigned short* vw = v_lds[wv];

    #define TOKOF(r) (tok_base + (r) + 90 * ((r) / 6))

    short8 z8 = {};
    for (int e = lane; e < 224; e += 64) {
        if (e < 128) {
            int ch = e >> 2, kst = 32 + (e & 3) * 8;
            *(short8*)(vw + ch * 64 + (kst ^ ((ch & 7) << 3))) = z8;
        } else {
            int ee = e - 128; int q = ee >> 1, kst = 48 + (ee & 1) * 8;
            *(short8*)(pw + q * 64 + (kst ^ ((q & 7) << 3))) = z8;
        }
    }

    for (int e = lane; e < 144; e += 64) {
        int r = e >> 2, c0 = (e & 3) * 8;
        short8 vv = *(const short8*)(qkv + (size_t)TOKOF(r) * 1536 + 1024 + h * 32 + c0);
#pragma unroll
        for (int j = 0; j < 8; ++j) {
            int ch = c0 + j;
            vw[ch * 64 + (r ^ ((ch & 7) << 3))] = (unsigned short)vv[j];
        }
    }

    short8 qf[3], kf[3];
#pragma unroll
    for (int t = 0; t < 3; ++t) {
        int r = t * 16 + l15;
        if (r < 36) {
            size_t ba = (size_t)TOKOF(r) * 1536 + h * 32 + g * 8;
            qf[t] = *(const short8*)(qkv + ba);
            kf[t] = *(const short8*)(qkv + ba + 512);
        } else { qf[t] = z8; kf[t] = z8; }
    }

    f32x4 s[3][3] = {};
#pragma unroll
    for (int mt = 0; mt < 3; ++mt)
#pragma unroll
        for (int nt = 0; nt < 3; ++nt)
            s[mt][nt] = __builtin_amdgcn_mfma_f32_16x16x32_bf16(qf[mt], kf[nt], s[mt][nt], 0, 0, 0);

    const float SCALE = 0.17677669529663687f;  // 1/sqrt(32)
    const float* bh = biasb + h * 2304;
#pragma unroll
    for (int mt = 0; mt < 3; ++mt) {
#pragma unroll
        for (int r = 0; r < 4; ++r) {
            int row = mt * 16 + g * 4 + r;
            const float* bb = bh + row * 48 + l15;
            float v0 = fmaf(s[mt][0][r], SCALE, bb[0]);
            float v1 = fmaf(s[mt][1][r], SCALE, bb[16]);
            float v2 = fmaf(s[mt][2][r], SCALE, bb[32]);
            float m = fmaxf(fmaxf(v0, v1), v2);
#pragma unroll
            for (int off = 1; off < 16; off <<= 1) m = fmaxf(m, __shfl_xor(m, off));
            float e0 = __expf(v0 - m), e1 = __expf(v1 - m), e2 = __expf(v2 - m);
            float sm = e0 + e1 + e2;
#pragma unroll
            for (int off = 1; off < 16; off <<= 1) sm += __shfl_xor(sm, off);
            float inv = 1.f / sm;
            int sw = (row & 7) << 3;
            unsigned short* pr = pw + row * 64;
            pr[(l15)      ^ sw] = f2bf(e0 * inv);
            pr[(16 + l15) ^ sw] = f2bf(e1 * inv);
            pr[(32 + l15) ^ sw] = f2bf(e2 * inv);
        }
    }

    f32x4 oacc[3][2] = {};
#pragma unroll
    for (int ks = 0; ks < 2; ++ks) {
        int kst = ks * 32 + g * 8;
        short8 bfr[2];
#pragma unroll
        for (int nt = 0; nt < 2; ++nt) {
            int c = nt * 16 + l15;
            bfr[nt] = *(const short8*)(vw + c * 64 + (kst ^ ((c & 7) << 3)));
        }
#pragma unroll
        for (int mt = 0; mt < 3; ++mt) {
            int q = mt * 16 + l15;
            short8 pa = *(const short8*)(pw + q * 64 + (kst ^ ((q & 7) << 3)));
#pragma unroll
            for (int nt = 0; nt < 2; ++nt)
                oacc[mt][nt] = __builtin_amdgcn_mfma_f32_16x16x32_bf16(pa, bfr[nt], oacc[mt][nt], 0, 0, 0);
        }
    }

#pragma unroll
    for (int mt = 0; mt < 3; ++mt) {
#pragma unroll
        for (int r = 0; r < 4; ++r) {
            int q = mt * 16 + g * 4 + r;
            if (q < 36) {
                size_t rb = (size_t)TOKOF(q) * 512 + h * 32;
#pragma unroll
                for (int nt = 0; nt < 2; ++nt)
                    o[rb + nt * 16 + l15] = f2bf(oacc[mt][nt][r]);
            }
        }
    }
    #undef TOKOF
}

// ---------------- 256^2-tile pipelined bf16 MFMA GEMM (ring-4 K-slots, counted vmcnt)
// C = A (MxK) * Bt^T (Bt is NxK). 512 threads = 8 waves (2M x 4N), per-wave 128x64.
// LDS: 4 ring slots x (A 16KB + B 16KB) = 128KB dynamic.
// EPI: 0 = bf16 store; 1 = f32 + bias; 2 = bf16 gelu(x+bias); 3 = f32 (x+bias+resid)
template <int EPI>
__global__ __launch_bounds__(512, 2) void gemm8(const unsigned short* __restrict__ A,
                                                const unsigned short* __restrict__ Bt,
                                                int M, int N, int K,
                                                const float* __restrict__ bias,
                                                const float* __restrict__ resid,
                                                void* __restrict__ Cout) {
    extern __shared__ char lds[];
    int tid = threadIdx.x;
    int w = tid >> 6, lane = tid & 63;
    int l15 = lane & 15, grp = lane >> 4;
    int wm = w >> 2, wn = w & 3;

    int nbn = N >> 8;
    int nwg = gridDim.x;
    // bijective XCD swizzle (m204)
    int q = nwg >> 3, r = nwg & 7;
    int xcd = blockIdx.x & 7, pos = blockIdx.x >> 3;
    int wgid = (xcd < r ? xcd * (q + 1) : r * (q + 1) + (xcd - r) * q) + pos;
    int bm = wgid / nbn, bn = wgid % nbn;

    int NSLOT = K >> 5;   // 32 kcols per slot

    // ---- staging addressing: granule p = (w*2+j)*64+lane; row=p>>2, gpos=p&3,
    //      stored global granule g = gpos ^ ((row>>1)&3)   (pre-swizzled source)
    int srow = w * 32 + (lane >> 2);
    int g0 = (lane & 3) ^ ((srow >> 1) & 3);
    const unsigned short* aSrc = A  + (size_t)(bm * 256 + srow) * K + g0 * 8;
    const unsigned short* bSrc = Bt + (size_t)(bn * 256 + srow) * K + g0 * 8;
    int ldst = w * 2048 + lane * 16;   // byte offset of j=0 dest; j=1: +1024

    #define STAGE(s) { \
        size_t ko = (size_t)(s) * 32; \
        char* sb_ = lds + ((s) & 3) * 32768; \
        gload16(aSrc + ko, sb_ + ldst); \
        gload16(aSrc + ko + (size_t)16 * K, sb_ + ldst + 1024); \
        gload16(bSrc + ko, sb_ + 16384 + ldst); \
        gload16(bSrc + ko + (size_t)16 * K, sb_ + 16384 + ldst + 1024); \
    }

    // ---- fragment read addressing (swizzled, 2-way bank = free)
    int gpos = grp ^ ((l15 >> 1) & 3);
    int aoff = (wm * 128 + l15) * 64 + gpos * 16;            // + m*1024
    int boff = 16384 + (wn * 64 + l15) * 64 + gpos * 16;     // + n*1024

    f32x4 acc[8][4] = {};

    STAGE(0); STAGE(1); STAGE(2);

    for (int s = 0; s < NSLOT; ++s) {
        int ahead = NSLOT - 1 - s;
        if (ahead >= 3) {
            STAGE(s + 3);
            asm volatile("s_waitcnt vmcnt(12)" ::: "memory");
        } else if (ahead == 2) {
            asm volatile("s_waitcnt vmcnt(8)" ::: "memory");
        } else if (ahead == 1) {
            asm volatile("s_waitcnt vmcnt(4)" ::: "memory");
        } else {
            asm volatile("s_waitcnt vmcnt(0)" ::: "memory");
        }
        asm volatile("s_barrier" ::: "memory");   // everyone's slot-s loads landed
        char* sb = lds + (s & 3) * 32768;
        short8 af[8], bf4[4];
#pragma unroll
        for (int m = 0; m < 8; ++m) af[m] = *(const short8*)(sb + aoff + m * 1024);
#pragma unroll
        for (int n = 0; n < 4; ++n) bf4[n] = *(const short8*)(sb + boff + n * 1024);
        asm volatile("s_waitcnt lgkmcnt(0)" ::: "memory");  // my reads in regs
        asm volatile("s_barrier" ::: "memory");   // slot-s region free for restage
        __builtin_amdgcn_sched_barrier(0);
        __builtin_amdgcn_s_setprio(1);
#pragma unroll
        for (int m = 0; m < 8; ++m)
#pragma unroll
            for (int n = 0; n < 4; ++n)
                acc[m][n] = __builtin_amdgcn_mfma_f32_16x16x32_bf16(af[m], bf4[n], acc[m][n], 0, 0, 0);
        __builtin_amdgcn_s_setprio(0);
    }
    #undef STAGE

    // ---- epilogue
    int row0 = bm * 256 + wm * 128 + grp * 4;
    int col0 = bn * 256 + wn * 64 + l15;
#pragma unroll
    for (int m = 0; m < 8; ++m) {
#pragma unroll
        for (int n = 0; n < 4; ++n) {
            int col = col0 + n * 16;
            float bv = (EPI == 0) ? 0.f : bias[col];
#pragma unroll
            for (int r2 = 0; r2 < 4; ++r2) {
                int row = row0 + m * 16 + r2;
                size_t idx = (size_t)row * N + col;
                float val = acc[m][n][r2] + bv;
                if (EPI == 0) {
                    ((unsigned short*)Cout)[idx] = f2bf(val);
                } else if (EPI == 1) {
                    ((float*)Cout)[idx] = val;
                } else if (EPI == 2) {
                    float ge = 0.5f * val * (1.f + erff(val * 0.70710678118654752f));
                    ((unsigned short*)Cout)[idx] = f2bf(ge);
                } else {
                    ((float*)Cout)[idx] = val + resid[idx];
                }
            }
        }
    }
}

extern "C" void kernel_launch(void* const* d_in, const int* in_sizes, int n_in,
                              void* d_out, int out_size, void* d_ws, size_t ws_size,
                              hipStream_t stream) {
    const float* x       = (const float*)d_in[0];
    const float* w_qkv   = (const float*)d_in[1];
    const float* w_proj  = (const float*)d_in[2];
    const float* b_proj  = (const float*)d_in[3];
    const float* relb    = (const float*)d_in[4];
    const float* ln1g    = (const float*)d_in[5];
    const float* ln1b    = (const float*)d_in[6];
    const float* ln2g    = (const float*)d_in[7];
    const float* ln2b    = (const float*)d_in[8];
    const float* w_fc1   = (const float*)d_in[9];
    const float* b_fc1   = (const float*)d_in[10];
    const float* w_fc2   = (const float*)d_in[11];
    const float* b_fc2   = (const float*)d_in[12];
    float* out = (float*)d_out;

    // allow 128KB dynamic LDS (host-side attribute, not a stream op)
    hipFuncSetAttribute(reinterpret_cast<const void*>(&gemm8<0>),
                        hipFuncAttributeMaxDynamicSharedMemorySize, 131072);
    hipFuncSetAttribute(reinterpret_cast<const void*>(&gemm8<1>),
                        hipFuncAttributeMaxDynamicSharedMemorySize, 131072);
    hipFuncSetAttribute(reinterpret_cast<const void*>(&gemm8<2>),
                        hipFuncAttributeMaxDynamicSharedMemorySize, 131072);
    hipFuncSetAttribute(reinterpret_cast<const void*>(&gemm8<3>),
                        hipFuncAttributeMaxDynamicSharedMemorySize, 131072);

    char* w = (char*)d_ws;
    unsigned short* wT_qkv  = (unsigned short*)w; w += (size_t)1536 * 512 * 2;
    unsigned short* wT_proj = (unsigned short*)w; w += (size_t)512  * 512 * 2;
    unsigned short* wT_fc1  = (unsigned short*)w; w += (size_t)2048 * 512 * 2;
    unsigned short* wT_fc2  = (unsigned short*)w; w += (size_t)512  * 2048 * 2;
    float* biasb            = (float*)w;          w += (size_t)16 * 48 * 48 * 4;
    size_t wbytes = (size_t)(w - (char*)d_ws);

    int nchunk = 16;
    for (int c = 1; c <= 16; c *= 2) {
        size_t tokc = TOK / c;
        if (wbytes + tokc * 1024 + tokc * 4096 <= ws_size) { nchunk = c; break; }
    }
    size_t tokc = TOK / nchunk;
    unsigned short* buf1 = (unsigned short*)w;
    unsigned short* buf2 = (unsigned short*)(w + tokc * 1024);

    wprep<<<(512 * 1536 + 255) / 256, 256, 0, stream>>>(w_qkv,  wT_qkv,  512, 1536);
    wprep<<<(512 * 512  + 255) / 256, 256, 0, stream>>>(w_proj, wT_proj, 512, 512);
    wprep<<<(512 * 2048 + 255) / 256, 256, 0, stream>>>(w_fc1,  wT_fc1,  512, 2048);
    wprep<<<(2048 * 512 + 255) / 256, 256, 0, stream>>>(w_fc2,  wT_fc2,  2048, 512);
    biasprep<<<(16 * 48 * 48 + 255) / 256, 256, 0, stream>>>(relb, biasb);

    int Mc = (int)tokc;
    int gm = Mc / 256;
    int imgs = Mc / 9216;

    for (int c = 0; c < nchunk; ++c) {
        size_t toff = (size_t)c * tokc;
        const float* xc = x + toff * CCH;
        float* outc = out + toff * CCH;

        ln_k<<<Mc / 4, 256, 0, stream>>>(xc, ln1g, ln1b, buf1, Mc);
        gemm8<0><<<gm * 6, 512, 131072, stream>>>(buf1, wT_qkv, Mc, 1536, 512,
                                                  nullptr, nullptr, buf2);
        attn_mfma<<<imgs * 1024, 256, 0, stream>>>(buf2, biasb, buf1);
        gemm8<1><<<gm * 2, 512, 131072, stream>>>(buf1, wT_proj, Mc, 512, 512,
                                                  b_proj, nullptr, outc);
        ln_k<<<Mc / 4, 256, 0, stream>>>(outc, ln2g, ln2b, buf1, Mc);
        gemm8<2><<<gm * 8, 512, 131072, stream>>>(buf1, wT_fc1, Mc, 2048, 512,
                                                  b_fc1, nullptr, buf2);
        gemm8<3><<<gm * 2, 512, 131072, stream>>>(buf2, wT_fc2, Mc, 512, 2048,
                                                  b_fc2, outc, outc);
    }
}

// Round 4
// 1767.143 us; speedup vs baseline: 1.5478x; 1.0568x over previous
//
#include <hip/hip_runtime.h>
#include <stdint.h>

#define TOK 147456   // 16*96*96
#define CCH 512

typedef __attribute__((ext_vector_type(8))) short short8;
typedef __attribute__((ext_vector_type(4))) float f32x4;

struct alignas(8) US4 { unsigned short a, b, c, d; };

typedef __attribute__((address_space(3))) void lds_void;
typedef const __attribute__((address_space(1))) void gbl_void;

__device__ inline void gload16(const void* g, void* l) {
    __builtin_amdgcn_global_load_lds((gbl_void*)g, (lds_void*)l, 16, 0, 0);
}

__device__ inline unsigned short f2bf(float f) {
    union { float f; unsigned u; } v{f};
    unsigned r = v.u + 0x7fffu + ((v.u >> 16) & 1u);
    return (unsigned short)(r >> 16);
}
__device__ inline float bf2f(unsigned short h) {
    union { unsigned u; float f; } v; v.u = ((unsigned)h) << 16; return v.f;
}

// ---------------- weight transpose + cast:  in (K x N) f32 -> out (N x K) bf16
__global__ void wprep(const float* __restrict__ in, unsigned short* __restrict__ out,
                      int K, int N) {
    int idx = blockIdx.x * 256 + threadIdx.x;
    if (idx >= K * N) return;
    int k = idx / N, n = idx % N;              // coalesced read
    out[(size_t)n * K + k] = f2bf(in[idx]);
}

// ---------------- rel_bias -> dense (16,48,48) f32 table, padded with -1e9
__global__ void biasprep(const float* __restrict__ rb, float* __restrict__ bb) {
    int idx = blockIdx.x * 256 + threadIdx.x;
    if (idx >= 16 * 48 * 48) return;
    int h = idx / 2304, rem = idx % 2304, r = rem / 48, c = rem % 48;
    float v = -1e9f;
    if (r < 36 && c < 36) {
        int dy = r / 6 - c / 6 + 5;
        int dx = r % 6 - c % 6 + 5;
        v = rb[(dy * 11 + dx) * 16 + h];
    }
    bb[idx] = v;
}

// ---------------- LayerNorm over C=512, one wave per token, out bf16
__global__ __launch_bounds__(256) void ln_k(const float* __restrict__ x,
                                            const float* __restrict__ g,
                                            const float* __restrict__ b,
                                            unsigned short* __restrict__ out, int ntok) {
    int lane = threadIdx.x & 63;
    int tok = blockIdx.x * 4 + (threadIdx.x >> 6);
    if (tok >= ntok) return;
    const float4* xr = (const float4*)(x + (size_t)tok * CCH);
    float4 v0 = xr[lane], v1 = xr[lane + 64];
    float s  = v0.x + v0.y + v0.z + v0.w + v1.x + v1.y + v1.z + v1.w;
    float s2 = v0.x*v0.x + v0.y*v0.y + v0.z*v0.z + v0.w*v0.w
             + v1.x*v1.x + v1.y*v1.y + v1.z*v1.z + v1.w*v1.w;
#pragma unroll
    for (int off = 32; off; off >>= 1) { s += __shfl_xor(s, off); s2 += __shfl_xor(s2, off); }
    float mean = s * (1.f / 512.f);
    float var  = s2 * (1.f / 512.f) - mean * mean;
    float inv  = rsqrtf(var + 1e-5f);
    const float4* gp = (const float4*)g;
    const float4* bp = (const float4*)b;
    float4 g0 = gp[lane], g1 = gp[lane + 64], b0 = bp[lane], b1 = bp[lane + 64];
    US4 o0, o1;
    o0.a = f2bf((v0.x - mean) * inv * g0.x + b0.x);
    o0.b = f2bf((v0.y - mean) * inv * g0.y + b0.y);
    o0.c = f2bf((v0.z - mean) * inv * g0.z + b0.z);
    o0.d = f2bf((v0.w - mean) * inv * g0.w + b0.w);
    o1.a = f2bf((v1.x - mean) * inv * g1.x + b1.x);
    o1.b = f2bf((v1.y - mean) * inv * g1.y + b1.y);
    o1.c = f2bf((v1.z - mean) * inv * g1.z + b1.z);
    o1.d = f2bf((v1.w - mean) * inv * g1.w + b1.w);
    unsigned short* op = out + (size_t)tok * CCH;
    *(US4*)(op + 4 * lane)       = o0;
    *(US4*)(op + 256 + 4 * lane) = o1;
}

// ---------------- MFMA windowed attention: one wave per (window, head)
__global__ __launch_bounds__(256) void attn_mfma(const unsigned short* __restrict__ qkv,
                                                 const float* __restrict__ biasb,
                                                 unsigned short* __restrict__ o) {
    __shared__ __align__(16) unsigned short p_lds[4][48 * 64];
    __shared__ __align__(16) unsigned short v_lds[4][32 * 64];

    int tid  = threadIdx.x;
    int wv   = tid >> 6;
    int lane = tid & 63;
    int l15  = lane & 15;
    int g    = lane >> 4;

    int wid = blockIdx.x * 4 + wv;
    int h   = wid & 15;
    int win = wid >> 4;
    int img  = win >> 8;
    int wrow = (win >> 4) & 15;
    int wcol = win & 15;
    int tok_base = (img * 96 + wrow * 6) * 96 + wcol * 6;

    unsigned short* pw = p_lds[wv];
    unsigned short* vw = v_lds[wv];

    #define TOKOF(r) (tok_base + (r) + 90 * ((r) / 6))

    short8 z8 = {};
    for (int e = lane; e < 224; e += 64) {
        if (e < 128) {
            int ch = e >> 2, kst = 32 + (e & 3) * 8;
            *(short8*)(vw + ch * 64 + (kst ^ ((ch & 7) << 3))) = z8;
        } else {
            int ee = e - 128; int q = ee >> 1, kst = 48 + (ee & 1) * 8;
            *(short8*)(pw + q * 64 + (kst ^ ((q & 7) << 3))) = z8;
        }
    }

    for (int e = lane; e < 144; e += 64) {
        int r = e >> 2, c0 = (e & 3) * 8;
        short8 vv = *(const short8*)(qkv + (size_t)TOKOF(r) * 1536 + 1024 + h * 32 + c0);
#pragma unroll
        for (int j = 0; j < 8; ++j) {
            int ch = c0 + j;
            vw[ch * 64 + (r ^ ((ch & 7) << 3))] = (unsigned short)vv[j];
        }
    }

    short8 qf[3], kf[3];
#pragma unroll
    for (int t = 0; t < 3; ++t) {
        int r = t * 16 + l15;
        if (r < 36) {
            size_t ba = (size_t)TOKOF(r) * 1536 + h * 32 + g * 8;
            qf[t] = *(const short8*)(qkv + ba);
            kf[t] = *(const short8*)(qkv + ba + 512);
        } else { qf[t] = z8; kf[t] = z8; }
    }

    f32x4 s[3][3] = {};
#pragma unroll
    for (int mt = 0; mt < 3; ++mt)
#pragma unroll
        for (int nt = 0; nt < 3; ++nt)
            s[mt][nt] = __builtin_amdgcn_mfma_f32_16x16x32_bf16(qf[mt], kf[nt], s[mt][nt], 0, 0, 0);

    const float SCALE = 0.17677669529663687f;  // 1/sqrt(32)
    const float* bh = biasb + h * 2304;
#pragma unroll
    for (int mt = 0; mt < 3; ++mt) {
#pragma unroll
        for (int r = 0; r < 4; ++r) {
            int row = mt * 16 + g * 4 + r;
            const float* bb = bh + row * 48 + l15;
            float v0 = fmaf(s[mt][0][r], SCALE, bb[0]);
            float v1 = fmaf(s[mt][1][r], SCALE, bb[16]);
            float v2 = fmaf(s[mt][2][r], SCALE, bb[32]);
            float m = fmaxf(fmaxf(v0, v1), v2);
#pragma unroll
            for (int off = 1; off < 16; off <<= 1) m = fmaxf(m, __shfl_xor(m, off));
            float e0 = __expf(v0 - m), e1 = __expf(v1 - m), e2 = __expf(v2 - m);
            float sm = e0 + e1 + e2;
#pragma unroll
            for (int off = 1; off < 16; off <<= 1) sm += __shfl_xor(sm, off);
            float inv = 1.f / sm;
            int sw = (row & 7) << 3;
            unsigned short* pr = pw + row * 64;
            pr[(l15)      ^ sw] = f2bf(e0 * inv);
            pr[(16 + l15) ^ sw] = f2bf(e1 * inv);
            pr[(32 + l15) ^ sw] = f2bf(e2 * inv);
        }
    }

    f32x4 oacc[3][2] = {};
#pragma unroll
    for (int ks = 0; ks < 2; ++ks) {
        int kst = ks * 32 + g * 8;
        short8 bfr[2];
#pragma unroll
        for (int nt = 0; nt < 2; ++nt) {
            int c = nt * 16 + l15;
            bfr[nt] = *(const short8*)(vw + c * 64 + (kst ^ ((c & 7) << 3)));
        }
#pragma unroll
        for (int mt = 0; mt < 3; ++mt) {
            int q = mt * 16 + l15;
            short8 pa = *(const short8*)(pw + q * 64 + (kst ^ ((q & 7) << 3)));
#pragma unroll
            for (int nt = 0; nt < 2; ++nt)
                oacc[mt][nt] = __builtin_amdgcn_mfma_f32_16x16x32_bf16(pa, bfr[nt], oacc[mt][nt], 0, 0, 0);
        }
    }

#pragma unroll
    for (int mt = 0; mt < 3; ++mt) {
#pragma unroll
        for (int r = 0; r < 4; ++r) {
            int q = mt * 16 + g * 4 + r;
            if (q < 36) {
                size_t rb = (size_t)TOKOF(q) * 512 + h * 32;
#pragma unroll
                for (int nt = 0; nt < 2; ++nt)
                    o[rb + nt * 16 + l15] = f2bf(oacc[mt][nt][r]);
            }
        }
    }
    #undef TOKOF
}

// ---------------- 256^2-tile pipelined bf16 MFMA GEMM
// ring-2 double buffer, BK=64 (128B rows, 8-granule XOR swizzle), quadrant
// fine-interleave, counted vmcnt(8). C = A (MxK) * Bt^T (Bt is NxK).
// 512 threads = 8 waves (2M x 4N), per-wave 128x64 output.
// LDS: 2 bufs x (A 32KB + B 32KB) = 128KB dynamic.
// EPI: 0 = bf16 store; 1 = f32 + bias; 2 = bf16 gelu(x+bias); 3 = f32 (x+bias+resid)
template <int EPI>
__global__ __launch_bounds__(512, 2) void gemm8(const unsigned short* __restrict__ A,
                                                const unsigned short* __restrict__ Bt,
                                                int M, int N, int K,
                                                const float* __restrict__ bias,
                                                const float* __restrict__ resid,
                                                void* __restrict__ Cout) {
    extern __shared__ char lds[];
    int tid = threadIdx.x;
    int w = tid >> 6, lane = tid & 63;
    int l15 = lane & 15, grp = lane >> 4;
    int wm = w >> 2, wn = w & 3;

    int nbn = N >> 8;
    int nwg = gridDim.x;
    // bijective XCD swizzle (m204)
    int q = nwg >> 3, r = nwg & 7;
    int xcd = blockIdx.x & 7, pos = blockIdx.x >> 3;
    int wgid = (xcd < r ? xcd * (q + 1) : r * (q + 1) + (xcd - r) * q) + pos;
    int bm = wgid / nbn, bn = wgid % nbn;

    int NT = K >> 6;   // 64 kcols per tile

    // ---- staging: dest (row, g) holds global granule g ^ (row&7); dest linear.
    //      thread t, load j: row = j*64 + (t>>3), dest g = t&7,
    //      src granule = (t&7) ^ ((t>>3)&7)  (j*64 = 0 mod 8)
    int sg = (tid & 7) ^ ((tid >> 3) & 7);
    const unsigned short* aSrc = A  + ((size_t)bm * 256 + (tid >> 3)) * (size_t)K + sg * 8;
    const unsigned short* bSrc = Bt + ((size_t)bn * 256 + (tid >> 3)) * (size_t)K + sg * 8;

    #define STAGE(t) do { \
        char* base_ = lds + ((t) & 1) * 65536; \
        size_t ko_ = (size_t)(t) * 64; \
        gload16(aSrc + ko_,                      base_ + 0 * 8192 + tid * 16); \
        gload16(aSrc + ko_ + (size_t)64  * K,    base_ + 1 * 8192 + tid * 16); \
        gload16(aSrc + ko_ + (size_t)128 * K,    base_ + 2 * 8192 + tid * 16); \
        gload16(aSrc + ko_ + (size_t)192 * K,    base_ + 3 * 8192 + tid * 16); \
        gload16(bSrc + ko_,                      base_ + 32768 + 0 * 8192 + tid * 16); \
        gload16(bSrc + ko_ + (size_t)64  * K,    base_ + 32768 + 1 * 8192 + tid * 16); \
        gload16(bSrc + ko_ + (size_t)128 * K,    base_ + 32768 + 2 * 8192 + tid * 16); \
        gload16(bSrc + ko_ + (size_t)192 * K,    base_ + 32768 + 3 * 8192 + tid * 16); \
    } while (0)

    // ---- fragment read addressing: row*128 + ((k*4+grp) ^ (row&7))*16; row&7 == l15&7
    int l7 = l15 & 7;
    int aBase = (wm * 128 + l15) * 128 + ((grp ^ l7) * 16);
    int bBase = 32768 + (wn * 64 + l15) * 128 + ((grp ^ l7) * 16);

    f32x4 acc[8][4] = {};

    STAGE(0);

    for (int t = 0; t < NT; ++t) {
        if (t + 1 < NT) {
            STAGE(t + 1);
            asm volatile("s_waitcnt vmcnt(8)" ::: "memory");   // tile t landed, t+1 flying
        } else {
            asm volatile("s_waitcnt vmcnt(0)" ::: "memory");
        }
        __builtin_amdgcn_s_barrier();            // everyone's tile-t loads visible
        char* sb = lds + (t & 1) * 65536;

        short8 af[4][2], bf[4][2];
        // R1: A rows m0-3 + B cols n0-1  (12 reads)
#pragma unroll
        for (int m = 0; m < 4; ++m) {
            int o_ = aBase + m * 2048;
            af[m][0] = *(const short8*)(sb + o_);
            af[m][1] = *(const short8*)(sb + (o_ ^ 64));
        }
#pragma unroll
        for (int n = 0; n < 2; ++n) {
            int o_ = bBase + n * 2048;
            bf[n][0] = *(const short8*)(sb + o_);
            bf[n][1] = *(const short8*)(sb + (o_ ^ 64));
        }
        // q0: m0-3 x n0-1
        __builtin_amdgcn_s_setprio(1);
#pragma unroll
        for (int m = 0; m < 4; ++m)
#pragma unroll
            for (int n = 0; n < 2; ++n)
#pragma unroll
                for (int k = 0; k < 2; ++k)
                    acc[m][n] = __builtin_amdgcn_mfma_f32_16x16x32_bf16(af[m][k], bf[n][k], acc[m][n], 0, 0, 0);
        __builtin_amdgcn_s_setprio(0);
        __builtin_amdgcn_sched_barrier(0);
        // R2: B cols n2-3 (4 reads)
#pragma unroll
        for (int n = 2; n < 4; ++n) {
            int o_ = bBase + n * 2048;
            bf[n][0] = *(const short8*)(sb + o_);
            bf[n][1] = *(const short8*)(sb + (o_ ^ 64));
        }
        // q2: m0-3 x n2-3
        __builtin_amdgcn_s_setprio(1);
#pragma unroll
        for (int m = 0; m < 4; ++m)
#pragma unroll
            for (int n = 2; n < 4; ++n)
#pragma unroll
                for (int k = 0; k < 2; ++k)
                    acc[m][n] = __builtin_amdgcn_mfma_f32_16x16x32_bf16(af[m][k], bf[n][k], acc[m][n], 0, 0, 0);
        __builtin_amdgcn_s_setprio(0);
        __builtin_amdgcn_sched_barrier(0);
        // R3: A rows m4-7 (8 reads, reuse af regs)
#pragma unroll
        for (int m = 0; m < 4; ++m) {
            int o_ = aBase + (m + 4) * 2048;
            af[m][0] = *(const short8*)(sb + o_);
            af[m][1] = *(const short8*)(sb + (o_ ^ 64));
        }
        // q1: m4-7 x n0-1
        __builtin_amdgcn_s_setprio(1);
#pragma unroll
        for (int m = 0; m < 4; ++m)
#pragma unroll
            for (int n = 0; n < 2; ++n)
#pragma unroll
                for (int k = 0; k < 2; ++k)
                    acc[m + 4][n] = __builtin_amdgcn_mfma_f32_16x16x32_bf16(af[m][k], bf[n][k], acc[m + 4][n], 0, 0, 0);
        // q3: m4-7 x n2-3
#pragma unroll
        for (int m = 0; m < 4; ++m)
#pragma unroll
            for (int n = 2; n < 4; ++n)
#pragma unroll
                for (int k = 0; k < 2; ++k)
                    acc[m + 4][n] = __builtin_amdgcn_mfma_f32_16x16x32_bf16(af[m][k], bf[n][k], acc[m + 4][n], 0, 0, 0);
        __builtin_amdgcn_s_setprio(0);
        __builtin_amdgcn_sched_barrier(0);
        __builtin_amdgcn_s_barrier();            // all reads of buf (t&1) done -> restage ok
    }
    #undef STAGE

    // ---- epilogue
    int row0 = bm * 256 + wm * 128 + grp * 4;
    int col0 = bn * 256 + wn * 64 + l15;
#pragma unroll
    for (int m = 0; m < 8; ++m) {
#pragma unroll
        for (int n = 0; n < 4; ++n) {
            int col = col0 + n * 16;
            float bv = (EPI == 0) ? 0.f : bias[col];
#pragma unroll
            for (int r2 = 0; r2 < 4; ++r2) {
                int row = row0 + m * 16 + r2;
                size_t idx = (size_t)row * N + col;
                float val = acc[m][n][r2] + bv;
                if (EPI == 0) {
                    ((unsigned short*)Cout)[idx] = f2bf(val);
                } else if (EPI == 1) {
                    ((float*)Cout)[idx] = val;
                } else if (EPI == 2) {
                    // tanh-form gelu (|err| ~1e-3, well under bf16 tolerance)
                    float u3 = val * val * val;
                    float z2 = 1.5957691216f * (val + 0.044715f * u3);   // 2*0.79788456*(x+..)
                    float e = __expf(z2);
                    float th = 1.f - 2.f / (e + 1.f);
                    float ge = 0.5f * val * (1.f + th);
                    ((unsigned short*)Cout)[idx] = f2bf(ge);
                } else {
                    ((float*)Cout)[idx] = val + resid[idx];
                }
            }
        }
    }
}

extern "C" void kernel_launch(void* const* d_in, const int* in_sizes, int n_in,
                              void* d_out, int out_size, void* d_ws, size_t ws_size,
                              hipStream_t stream) {
    const float* x       = (const float*)d_in[0];
    const float* w_qkv   = (const float*)d_in[1];
    const float* w_proj  = (const float*)d_in[2];
    const float* b_proj  = (const float*)d_in[3];
    const float* relb    = (const float*)d_in[4];
    const float* ln1g    = (const float*)d_in[5];
    const float* ln1b    = (const float*)d_in[6];
    const float* ln2g    = (const float*)d_in[7];
    const float* ln2b    = (const float*)d_in[8];
    const float* w_fc1   = (const float*)d_in[9];
    const float* b_fc1   = (const float*)d_in[10];
    const float* w_fc2   = (const float*)d_in[11];
    const float* b_fc2   = (const float*)d_in[12];
    float* out = (float*)d_out;

    hipFuncSetAttribute(reinterpret_cast<const void*>(&gemm8<0>),
                        hipFuncAttributeMaxDynamicSharedMemorySize, 131072);
    hipFuncSetAttribute(reinterpret_cast<const void*>(&gemm8<1>),
                        hipFuncAttributeMaxDynamicSharedMemorySize, 131072);
    hipFuncSetAttribute(reinterpret_cast<const void*>(&gemm8<2>),
                        hipFuncAttributeMaxDynamicSharedMemorySize, 131072);
    hipFuncSetAttribute(reinterpret_cast<const void*>(&gemm8<3>),
                        hipFuncAttributeMaxDynamicSharedMemorySize, 131072);

    char* w = (char*)d_ws;
    unsigned short* wT_qkv  = (unsigned short*)w; w += (size_t)1536 * 512 * 2;
    unsigned short* wT_proj = (unsigned short*)w; w += (size_t)512  * 512 * 2;
    unsigned short* wT_fc1  = (unsigned short*)w; w += (size_t)2048 * 512 * 2;
    unsigned short* wT_fc2  = (unsigned short*)w; w += (size_t)512  * 2048 * 2;
    float* biasb            = (float*)w;          w += (size_t)16 * 48 * 48 * 4;
    size_t wbytes = (size_t)(w - (char*)d_ws);

    int nchunk = 16;
    for (int c = 1; c <= 16; c *= 2) {
        size_t tokc = TOK / c;
        if (wbytes + tokc * 1024 + tokc * 4096 <= ws_size) { nchunk = c; break; }
    }
    size_t tokc = TOK / nchunk;
    unsigned short* buf1 = (unsigned short*)w;
    unsigned short* buf2 = (unsigned short*)(w + tokc * 1024);

    wprep<<<(512 * 1536 + 255) / 256, 256, 0, stream>>>(w_qkv,  wT_qkv,  512, 1536);
    wprep<<<(512 * 512  + 255) / 256, 256, 0, stream>>>(w_proj, wT_proj, 512, 512);
    wprep<<<(512 * 2048 + 255) / 256, 256, 0, stream>>>(w_fc1,  wT_fc1,  512, 2048);
    wprep<<<(2048 * 512 + 255) / 256, 256, 0, stream>>>(w_fc2,  wT_fc2,  2048, 512);
    biasprep<<<(16 * 48 * 48 + 255) / 256, 256, 0, stream>>>(relb, biasb);

    int Mc = (int)tokc;
    int gm = Mc / 256;
    int imgs = Mc / 9216;

    for (int c = 0; c < nchunk; ++c) {
        size_t toff = (size_t)c * tokc;
        const float* xc = x + toff * CCH;
        float* outc = out + toff * CCH;

        ln_k<<<Mc / 4, 256, 0, stream>>>(xc, ln1g, ln1b, buf1, Mc);
        gemm8<0><<<gm * 6, 512, 131072, stream>>>(buf1, wT_qkv, Mc, 1536, 512,
                                                  nullptr, nullptr, buf2);
        attn_mfma<<<imgs * 1024, 256, 0, stream>>>(buf2, biasb, buf1);
        gemm8<1><<<gm * 2, 512, 131072, stream>>>(buf1, wT_proj, Mc, 512, 512,
                                                  b_proj, nullptr, outc);
        ln_k<<<Mc / 4, 256, 0, stream>>>(outc, ln2g, ln2b, buf1, Mc);
        gemm8<2><<<gm * 8, 512, 131072, stream>>>(buf1, wT_fc1, Mc, 2048, 512,
                                                  b_fc1, nullptr, buf2);
        gemm8<3><<<gm * 2, 512, 131072, stream>>>(buf2, wT_fc2, Mc, 512, 2048,
                                                  b_fc2, outc, outc);
    }
}

// Round 5
// 1681.628 us; speedup vs baseline: 1.6265x; 1.0509x over previous
//
#include <hip/hip_runtime.h>
#include <stdint.h>

#define TOK 147456   // 16*96*96
#define CCH 512

typedef __attribute__((ext_vector_type(8))) short short8;
typedef __attribute__((ext_vector_type(4))) float f32x4;

struct alignas(8) US4 { unsigned short a, b, c, d; };

typedef __attribute__((address_space(3))) void lds_void;
typedef const __attribute__((address_space(1))) void gbl_void;

__device__ inline void gload16(const void* g, void* l) {
    __builtin_amdgcn_global_load_lds((gbl_void*)g, (lds_void*)l, 16, 0, 0);
}

__device__ inline unsigned short f2bf(float f) {
    union { float f; unsigned u; } v{f};
    unsigned r = v.u + 0x7fffu + ((v.u >> 16) & 1u);
    return (unsigned short)(r >> 16);
}
__device__ inline float bf2f(unsigned short h) {
    union { unsigned u; float f; } v; v.u = ((unsigned)h) << 16; return v.f;
}

// ---------------- weight transpose + cast:  in (K x N) f32 -> out (N x K) bf16
__global__ void wprep(const float* __restrict__ in, unsigned short* __restrict__ out,
                      int K, int N) {
    int idx = blockIdx.x * 256 + threadIdx.x;
    if (idx >= K * N) return;
    int k = idx / N, n = idx % N;
    out[(size_t)n * K + k] = f2bf(in[idx]);
}

// ---------------- rel_bias -> dense (16,48,48) f32 table, padded with -1e9
__global__ void biasprep(const float* __restrict__ rb, float* __restrict__ bb) {
    int idx = blockIdx.x * 256 + threadIdx.x;
    if (idx >= 16 * 48 * 48) return;
    int h = idx / 2304, rem = idx % 2304, r = rem / 48, c = rem % 48;
    float v = -1e9f;
    if (r < 36 && c < 36) {
        int dy = r / 6 - c / 6 + 5;
        int dx = r % 6 - c % 6 + 5;
        v = rb[(dy * 11 + dx) * 16 + h];
    }
    bb[idx] = v;
}

// ---------------- LayerNorm over C=512 (f32 input), one wave per token, out bf16
__global__ __launch_bounds__(256) void ln_k(const float* __restrict__ x,
                                            const float* __restrict__ g,
                                            const float* __restrict__ b,
                                            unsigned short* __restrict__ out, int ntok) {
    int lane = threadIdx.x & 63;
    int tok = blockIdx.x * 4 + (threadIdx.x >> 6);
    if (tok >= ntok) return;
    const float4* xr = (const float4*)(x + (size_t)tok * CCH);
    float4 v0 = xr[lane], v1 = xr[lane + 64];
    float s  = v0.x + v0.y + v0.z + v0.w + v1.x + v1.y + v1.z + v1.w;
    float s2 = v0.x*v0.x + v0.y*v0.y + v0.z*v0.z + v0.w*v0.w
             + v1.x*v1.x + v1.y*v1.y + v1.z*v1.z + v1.w*v1.w;
#pragma unroll
    for (int off = 32; off; off >>= 1) { s += __shfl_xor(s, off); s2 += __shfl_xor(s2, off); }
    float mean = s * (1.f / 512.f);
    float var  = s2 * (1.f / 512.f) - mean * mean;
    float inv  = rsqrtf(var + 1e-5f);
    const float4* gp = (const float4*)g;
    const float4* bp = (const float4*)b;
    float4 g0 = gp[lane], g1 = gp[lane + 64], b0 = bp[lane], b1 = bp[lane + 64];
    US4 o0, o1;
    o0.a = f2bf((v0.x - mean) * inv * g0.x + b0.x);
    o0.b = f2bf((v0.y - mean) * inv * g0.y + b0.y);
    o0.c = f2bf((v0.z - mean) * inv * g0.z + b0.z);
    o0.d = f2bf((v0.w - mean) * inv * g0.w + b0.w);
    o1.a = f2bf((v1.x - mean) * inv * g1.x + b1.x);
    o1.b = f2bf((v1.y - mean) * inv * g1.y + b1.y);
    o1.c = f2bf((v1.z - mean) * inv * g1.z + b1.z);
    o1.d = f2bf((v1.w - mean) * inv * g1.w + b1.w);
    unsigned short* op = out + (size_t)tok * CCH;
    *(US4*)(op + 4 * lane)       = o0;
    *(US4*)(op + 256 + 4 * lane) = o1;
}

// ---------------- LayerNorm over C=512 (bf16 input), one wave per token, out bf16
__global__ __launch_bounds__(256) void ln_bf(const unsigned short* __restrict__ x,
                                             const float* __restrict__ g,
                                             const float* __restrict__ b,
                                             unsigned short* __restrict__ out, int ntok) {
    int lane = threadIdx.x & 63;
    int tok = blockIdx.x * 4 + (threadIdx.x >> 6);
    if (tok >= ntok) return;
    short8 v = *(const short8*)(x + (size_t)tok * CCH + lane * 8);
    float f[8];
#pragma unroll
    for (int j = 0; j < 8; ++j) f[j] = bf2f((unsigned short)v[j]);
    float s = 0.f, s2 = 0.f;
#pragma unroll
    for (int j = 0; j < 8; ++j) { s += f[j]; s2 += f[j] * f[j]; }
#pragma unroll
    for (int off = 32; off; off >>= 1) { s += __shfl_xor(s, off); s2 += __shfl_xor(s2, off); }
    float mean = s * (1.f / 512.f);
    float var  = s2 * (1.f / 512.f) - mean * mean;
    float inv  = rsqrtf(var + 1e-5f);
    const float4* gp = (const float4*)g + lane * 2;
    const float4* bp = (const float4*)b + lane * 2;
    float4 g0 = gp[0], g1 = gp[1], b0 = bp[0], b1 = bp[1];
    float gg[8] = {g0.x, g0.y, g0.z, g0.w, g1.x, g1.y, g1.z, g1.w};
    float bb[8] = {b0.x, b0.y, b0.z, b0.w, b1.x, b1.y, b1.z, b1.w};
    short8 o;
#pragma unroll
    for (int j = 0; j < 8; ++j) o[j] = (short)f2bf((f[j] - mean) * inv * gg[j] + bb[j]);
    *(short8*)(out + (size_t)tok * CCH + lane * 8) = o;
}

// ---------------- MFMA windowed attention: one wave per (window, head)
__global__ __launch_bounds__(256) void attn_mfma(const unsigned short* __restrict__ qkv,
                                                 const float* __restrict__ biasb,
                                                 unsigned short* __restrict__ o) {
    __shared__ __align__(16) unsigned short p_lds[4][48 * 64];
    __shared__ __align__(16) unsigned short v_lds[4][32 * 64];

    int tid  = threadIdx.x;
    int wv   = tid >> 6;
    int lane = tid & 63;
    int l15  = lane & 15;
    int g    = lane >> 4;

    int wid = blockIdx.x * 4 + wv;
    int h   = wid & 15;
    int win = wid >> 4;
    int img  = win >> 8;
    int wrow = (win >> 4) & 15;
    int wcol = win & 15;
    int tok_base = (img * 96 + wrow * 6) * 96 + wcol * 6;

    unsigned short* pw = p_lds[wv];
    unsigned short* vw = v_lds[wv];

    #define TOKOF(r) (tok_base + (r) + 90 * ((r) / 6))

    short8 z8 = {};
    for (int e = lane; e < 224; e += 64) {
        if (e < 128) {
            int ch = e >> 2, kst = 32 + (e & 3) * 8;
            *(short8*)(vw + ch * 64 + (kst ^ ((ch & 7) << 3))) = z8;
        } else {
            int ee = e - 128; int q = ee >> 1, kst = 48 + (ee & 1) * 8;
            *(short8*)(pw + q * 64 + (kst ^ ((q & 7) << 3))) = z8;
        }
    }

    for (int e = lane; e < 144; e += 64) {
        int r = e >> 2, c0 = (e & 3) * 8;
        short8 vv = *(const short8*)(qkv + (size_t)TOKOF(r) * 1536 + 1024 + h * 32 + c0);
#pragma unroll
        for (int j = 0; j < 8; ++j) {
            int ch = c0 + j;
            vw[ch * 64 + (r ^ ((ch & 7) << 3))] = (unsigned short)vv[j];
        }
    }

    short8 qf[3], kf[3];
#pragma unroll
    for (int t = 0; t < 3; ++t) {
        int r = t * 16 + l15;
        if (r < 36) {
            size_t ba = (size_t)TOKOF(r) * 1536 + h * 32 + g * 8;
            qf[t] = *(const short8*)(qkv + ba);
            kf[t] = *(const short8*)(qkv + ba + 512);
        } else { qf[t] = z8; kf[t] = z8; }
    }

    f32x4 s[3][3] = {};
#pragma unroll
    for (int mt = 0; mt < 3; ++mt)
#pragma unroll
        for (int nt = 0; nt < 3; ++nt)
            s[mt][nt] = __builtin_amdgcn_mfma_f32_16x16x32_bf16(qf[mt], kf[nt], s[mt][nt], 0, 0, 0);

    const float SCALE = 0.17677669529663687f;  // 1/sqrt(32)
    const float* bh = biasb + h * 2304;
#pragma unroll
    for (int mt = 0; mt < 3; ++mt) {
#pragma unroll
        for (int r = 0; r < 4; ++r) {
            int row = mt * 16 + g * 4 + r;
            const float* bb = bh + row * 48 + l15;
            float v0 = fmaf(s[mt][0][r], SCALE, bb[0]);
            float v1 = fmaf(s[mt][1][r], SCALE, bb[16]);
            float v2 = fmaf(s[mt][2][r], SCALE, bb[32]);
            float m = fmaxf(fmaxf(v0, v1), v2);
#pragma unroll
            for (int off = 1; off < 16; off <<= 1) m = fmaxf(m, __shfl_xor(m, off));
            float e0 = __expf(v0 - m), e1 = __expf(v1 - m), e2 = __expf(v2 - m);
            float sm = e0 + e1 + e2;
#pragma unroll
            for (int off = 1; off < 16; off <<= 1) sm += __shfl_xor(sm, off);
            float inv = 1.f / sm;
            int sw = (row & 7) << 3;
            unsigned short* pr = pw + row * 64;
            pr[(l15)      ^ sw] = f2bf(e0 * inv);
            pr[(16 + l15) ^ sw] = f2bf(e1 * inv);
            pr[(32 + l15) ^ sw] = f2bf(e2 * inv);
        }
    }

    f32x4 oacc[3][2] = {};
#pragma unroll
    for (int ks = 0; ks < 2; ++ks) {
        int kst = ks * 32 + g * 8;
        short8 bfr[2];
#pragma unroll
        for (int nt = 0; nt < 2; ++nt) {
            int c = nt * 16 + l15;
            bfr[nt] = *(const short8*)(vw + c * 64 + (kst ^ ((c & 7) << 3)));
        }
#pragma unroll
        for (int mt = 0; mt < 3; ++mt) {
            int q = mt * 16 + l15;
            short8 pa = *(const short8*)(pw + q * 64 + (kst ^ ((q & 7) << 3)));
#pragma unroll
            for (int nt = 0; nt < 2; ++nt)
                oacc[mt][nt] = __builtin_amdgcn_mfma_f32_16x16x32_bf16(pa, bfr[nt], oacc[mt][nt], 0, 0, 0);
        }
    }

#pragma unroll
    for (int mt = 0; mt < 3; ++mt) {
#pragma unroll
        for (int r = 0; r < 4; ++r) {
            int q = mt * 16 + g * 4 + r;
            if (q < 36) {
                size_t rb = (size_t)TOKOF(q) * 512 + h * 32;
#pragma unroll
                for (int nt = 0; nt < 2; ++nt)
                    o[rb + nt * 16 + l15] = f2bf(oacc[mt][nt][r]);
            }
        }
    }
    #undef TOKOF
}

// ---------------- 256^2-tile bf16 MFMA GEMM, m201-style phase rhythm
// ring-4 x BK=32 slots (32KB each, 128KB LDS). 512 thr = 8 waves (2M x 4N).
// Per K-tile: 2 phases, each {ds_read subtile; 2-load half-stage of t+3;
//   lgkmcnt(0); setprio(1); 16 MFMA; setprio(0); barrier}. vmcnt counted
//   8/4/0, never drained mid-loop.
// LDS layout per slot: A 16KB then B 16KB; row pair-interleaved XOR swizzle:
//   (row,granule g) at line=row>>1, pos=(g+(row&1)*4)^(line&7), byte=line*128+pos*16
// EPI: 0 = bf16; 1 = bf16 + bias; 2 = bf16 gelu(x+bias); 3 = f32 (x+bias+resid_bf16)
template <int EPI>
__global__ __launch_bounds__(512, 1) void gemm8(const unsigned short* __restrict__ A,
                                                const unsigned short* __restrict__ Bt,
                                                int M, int N, int K,
                                                const float* __restrict__ bias,
                                                const unsigned short* __restrict__ resid,
                                                void* __restrict__ Cout) {
    extern __shared__ char lds[];
    int tid = threadIdx.x;
    int w = tid >> 6, lane = tid & 63;
    int l15 = lane & 15, grp = lane >> 4;
    int wm = w >> 2, wn = w & 3;

    int nbn = N >> 8;
    int nwg = gridDim.x;
    int q = nwg >> 3, r = nwg & 7;
    int xcd = blockIdx.x & 7, pos_ = blockIdx.x >> 3;
    int wgid = (xcd < r ? xcd * (q + 1) : r * (q + 1) + (xcd - r) * q) + pos_;
    int bm = wgid / nbn, bn = wgid % nbn;

    int NT = K >> 5;   // K-tiles of 32

    // staging: dest linear (tid*16), source inverse-swizzled
    int u = (tid & 7) ^ ((tid >> 3) & 7);
    int srow = ((tid >> 3) << 1) + (u >> 2);   // + j*128
    int scol = (u & 3) * 8;
    const unsigned short* aSrc = A  + ((size_t)bm * 256 + srow) * (size_t)K + scol;
    const unsigned short* bSrc = Bt + ((size_t)bn * 256 + srow) * (size_t)K + scol;

    #define STAGE_A(t) do { char* s_ = lds + ((t) & 3) * 32768; size_t ko_ = (size_t)(t) * 32; \
        gload16(aSrc + ko_, s_ + tid * 16); \
        gload16(aSrc + ko_ + (size_t)128 * K, s_ + 8192 + tid * 16); } while (0)
    #define STAGE_B(t) do { char* s_ = lds + ((t) & 3) * 32768 + 16384; size_t ko_ = (size_t)(t) * 32; \
        gload16(bSrc + ko_, s_ + tid * 16); \
        gload16(bSrc + ko_ + (size_t)128 * K, s_ + 8192 + tid * 16); } while (0)

    // fragment read base: row = base + mi*16 + l15, k-granule = grp
    int rpos = (grp + (l15 & 1) * 4) ^ (l15 >> 1);
    int aRd = (wm * 64 + (l15 >> 1)) * 128 + rpos * 16;           // + mi*1024
    int bRd = 16384 + (wn * 32 + (l15 >> 1)) * 128 + rpos * 16;   // + ni*1024

    f32x4 acc[8][4] = {};

    STAGE_A(0); STAGE_B(0); STAGE_A(1); STAGE_B(1); STAGE_A(2); STAGE_B(2);
    asm volatile("s_waitcnt vmcnt(8)" ::: "memory");   // tile 0 landed
    __builtin_amdgcn_s_barrier();

    for (int t = 0; t < NT; ++t) {
        char* sb = lds + (t & 3) * 32768;
        short8 af[4], bf[4], ag[4];

        // ---- Phase 0: read af[0-3] + bf[0-3]; stage A(t+3); MFMA m0-3
#pragma unroll
        for (int m = 0; m < 4; ++m) af[m] = *(const short8*)(sb + aRd + m * 1024);
#pragma unroll
        for (int n = 0; n < 4; ++n) bf[n] = *(const short8*)(sb + bRd + n * 1024);
        if (t + 3 < NT) STAGE_A(t + 3);
        asm volatile("s_waitcnt lgkmcnt(0)" ::: "memory");
        __builtin_amdgcn_sched_barrier(0);
        __builtin_amdgcn_s_setprio(1);
#pragma unroll
        for (int m = 0; m < 4; ++m)
#pragma unroll
            for (int n = 0; n < 4; ++n)
                acc[m][n] = __builtin_amdgcn_mfma_f32_16x16x32_bf16(af[m], bf[n], acc[m][n], 0, 0, 0);
        __builtin_amdgcn_s_setprio(0);
        __builtin_amdgcn_s_barrier();

        // ---- Phase 1: read af[4-7]; stage B(t+3); tile-end vmcnt; MFMA m4-7
#pragma unroll
        for (int m = 0; m < 4; ++m) ag[m] = *(const short8*)(sb + aRd + (m + 4) * 1024);
        if (t + 3 < NT) STAGE_B(t + 3);
        if (t + 1 < NT) {
            if (t + 3 < NT)      asm volatile("s_waitcnt vmcnt(8)" ::: "memory");
            else if (t + 2 < NT) asm volatile("s_waitcnt vmcnt(4)" ::: "memory");
            else                 asm volatile("s_waitcnt vmcnt(0)" ::: "memory");
        }
        asm volatile("s_waitcnt lgkmcnt(0)" ::: "memory");
        __builtin_amdgcn_sched_barrier(0);
        __builtin_amdgcn_s_setprio(1);
#pragma unroll
        for (int m = 0; m < 4; ++m)
#pragma unroll
            for (int n = 0; n < 4; ++n)
                acc[m + 4][n] = __builtin_amdgcn_mfma_f32_16x16x32_bf16(ag[m], bf[n], acc[m + 4][n], 0, 0, 0);
        __builtin_amdgcn_s_setprio(0);
        __builtin_amdgcn_s_barrier();
    }
    #undef STAGE_A
    #undef STAGE_B

    // ---- epilogue
    int row0 = bm * 256 + wm * 128 + grp * 4;
    int col0 = bn * 256 + wn * 64 + l15;
#pragma unroll
    for (int m = 0; m < 8; ++m) {
#pragma unroll
        for (int n = 0; n < 4; ++n) {
            int col = col0 + n * 16;
            float bv = (EPI == 0) ? 0.f : bias[col];
#pragma unroll
            for (int r2 = 0; r2 < 4; ++r2) {
                int row = row0 + m * 16 + r2;
                size_t idx = (size_t)row * N + col;
                float val = acc[m][n][r2] + bv;
                if (EPI == 0) {
                    ((unsigned short*)Cout)[idx] = f2bf(val);
                } else if (EPI == 1) {
                    ((unsigned short*)Cout)[idx] = f2bf(val);
                } else if (EPI == 2) {
                    float u3 = val * val * val;
                    float z2 = 1.5957691216f * (val + 0.044715f * u3);
                    float e = __expf(z2);
                    float th = 1.f - 2.f / (e + 1.f);
                    float ge = 0.5f * val * (1.f + th);
                    ((unsigned short*)Cout)[idx] = f2bf(ge);
                } else {
                    ((float*)Cout)[idx] = val + bf2f(resid[idx]);
                }
            }
        }
    }
}

extern "C" void kernel_launch(void* const* d_in, const int* in_sizes, int n_in,
                              void* d_out, int out_size, void* d_ws, size_t ws_size,
                              hipStream_t stream) {
    const float* x       = (const float*)d_in[0];
    const float* w_qkv   = (const float*)d_in[1];
    const float* w_proj  = (const float*)d_in[2];
    const float* b_proj  = (const float*)d_in[3];
    const float* relb    = (const float*)d_in[4];
    const float* ln1g    = (const float*)d_in[5];
    const float* ln1b    = (const float*)d_in[6];
    const float* ln2g    = (const float*)d_in[7];
    const float* ln2b    = (const float*)d_in[8];
    const float* w_fc1   = (const float*)d_in[9];
    const float* b_fc1   = (const float*)d_in[10];
    const float* w_fc2   = (const float*)d_in[11];
    const float* b_fc2   = (const float*)d_in[12];
    float* out = (float*)d_out;

    hipFuncSetAttribute(reinterpret_cast<const void*>(&gemm8<0>),
                        hipFuncAttributeMaxDynamicSharedMemorySize, 131072);
    hipFuncSetAttribute(reinterpret_cast<const void*>(&gemm8<1>),
                        hipFuncAttributeMaxDynamicSharedMemorySize, 131072);
    hipFuncSetAttribute(reinterpret_cast<const void*>(&gemm8<2>),
                        hipFuncAttributeMaxDynamicSharedMemorySize, 131072);
    hipFuncSetAttribute(reinterpret_cast<const void*>(&gemm8<3>),
                        hipFuncAttributeMaxDynamicSharedMemorySize, 131072);

    char* w = (char*)d_ws;
    unsigned short* wT_qkv  = (unsigned short*)w; w += (size_t)1536 * 512 * 2;
    unsigned short* wT_proj = (unsigned short*)w; w += (size_t)512  * 512 * 2;
    unsigned short* wT_fc1  = (unsigned short*)w; w += (size_t)2048 * 512 * 2;
    unsigned short* wT_fc2  = (unsigned short*)w; w += (size_t)512  * 2048 * 2;
    float* biasb            = (float*)w;          w += (size_t)16 * 48 * 48 * 4;
    size_t wbytes = (size_t)(w - (char*)d_ws);

    // activation buffers: buf1 (512 bf16), buf2 (2048 bf16), buf3 (512 bf16, x2)
    int nchunk = 16;
    for (int c = 1; c <= 16; c *= 2) {
        size_t tokc = TOK / c;
        if (wbytes + tokc * 6144 <= ws_size) { nchunk = c; break; }
    }
    size_t tokc = TOK / nchunk;
    unsigned short* buf1 = (unsigned short*)w;
    unsigned short* buf2 = (unsigned short*)(w + tokc * 1024);
    unsigned short* buf3 = (unsigned short*)(w + tokc * 5120);

    wprep<<<(512 * 1536 + 255) / 256, 256, 0, stream>>>(w_qkv,  wT_qkv,  512, 1536);
    wprep<<<(512 * 512  + 255) / 256, 256, 0, stream>>>(w_proj, wT_proj, 512, 512);
    wprep<<<(512 * 2048 + 255) / 256, 256, 0, stream>>>(w_fc1,  wT_fc1,  512, 2048);
    wprep<<<(2048 * 512 + 255) / 256, 256, 0, stream>>>(w_fc2,  wT_fc2,  2048, 512);
    biasprep<<<(16 * 48 * 48 + 255) / 256, 256, 0, stream>>>(relb, biasb);

    int Mc = (int)tokc;
    int gm = Mc / 256;
    int imgs = Mc / 9216;

    for (int c = 0; c < nchunk; ++c) {
        size_t toff = (size_t)c * tokc;
        const float* xc = x + toff * CCH;
        float* outc = out + toff * CCH;

        ln_k<<<Mc / 4, 256, 0, stream>>>(xc, ln1g, ln1b, buf1, Mc);
        gemm8<0><<<gm * 6, 512, 131072, stream>>>(buf1, wT_qkv, Mc, 1536, 512,
                                                  nullptr, nullptr, buf2);
        attn_mfma<<<imgs * 1024, 256, 0, stream>>>(buf2, biasb, buf1);
        gemm8<1><<<gm * 2, 512, 131072, stream>>>(buf1, wT_proj, Mc, 512, 512,
                                                  b_proj, nullptr, buf3);
        ln_bf<<<Mc / 4, 256, 0, stream>>>(buf3, ln2g, ln2b, buf1, Mc);
        gemm8<2><<<gm * 8, 512, 131072, stream>>>(buf1, wT_fc1, Mc, 2048, 512,
                                                  b_fc1, nullptr, buf2);
        gemm8<3><<<gm * 2, 512, 131072, stream>>>(buf2, wT_fc2, Mc, 512, 2048,
                                                  b_fc2, buf3, outc);
    }
}

// Round 6
// 1662.464 us; speedup vs baseline: 1.6452x; 1.0115x over previous
//
#include <hip/hip_runtime.h>
#include <stdint.h>

#define TOK 147456   // 16*96*96
#define CCH 512

typedef __attribute__((ext_vector_type(8))) short short8;
typedef __attribute__((ext_vector_type(4))) float f32x4;

struct alignas(8) US4 { unsigned short a, b, c, d; };

typedef __attribute__((address_space(3))) void lds_void;
typedef const __attribute__((address_space(1))) void gbl_void;

__device__ inline void gload16(const void* g, void* l) {
    __builtin_amdgcn_global_load_lds((gbl_void*)g, (lds_void*)l, 16, 0, 0);
}

__device__ inline unsigned short f2bf(float f) {
    union { float f; unsigned u; } v{f};
    unsigned r = v.u + 0x7fffu + ((v.u >> 16) & 1u);
    return (unsigned short)(r >> 16);
}
__device__ inline float bf2f(unsigned short h) {
    union { unsigned u; float f; } v; v.u = ((unsigned)h) << 16; return v.f;
}

// ---------------- weight transpose + cast:  in (K x N) f32 -> out (N x K) bf16
__global__ void wprep(const float* __restrict__ in, unsigned short* __restrict__ out,
                      int K, int N) {
    int idx = blockIdx.x * 256 + threadIdx.x;
    if (idx >= K * N) return;
    int k = idx / N, n = idx % N;
    out[(size_t)n * K + k] = f2bf(in[idx]);
}

// ---------------- rel_bias -> dense (16,48,48) f32 table, padded with -1e9
__global__ void biasprep(const float* __restrict__ rb, float* __restrict__ bb) {
    int idx = blockIdx.x * 256 + threadIdx.x;
    if (idx >= 16 * 48 * 48) return;
    int h = idx / 2304, rem = idx % 2304, r = rem / 48, c = rem % 48;
    float v = -1e9f;
    if (r < 36 && c < 36) {
        int dy = r / 6 - c / 6 + 5;
        int dx = r % 6 - c % 6 + 5;
        v = rb[(dy * 11 + dx) * 16 + h];
    }
    bb[idx] = v;
}

// ---------------- LayerNorm over C=512 (f32 input), one wave per token, out bf16
__global__ __launch_bounds__(256) void ln_k(const float* __restrict__ x,
                                            const float* __restrict__ g,
                                            const float* __restrict__ b,
                                            unsigned short* __restrict__ out, int ntok) {
    int lane = threadIdx.x & 63;
    int tok = blockIdx.x * 4 + (threadIdx.x >> 6);
    if (tok >= ntok) return;
    const float4* xr = (const float4*)(x + (size_t)tok * CCH);
    float4 v0 = xr[lane], v1 = xr[lane + 64];
    float s  = v0.x + v0.y + v0.z + v0.w + v1.x + v1.y + v1.z + v1.w;
    float s2 = v0.x*v0.x + v0.y*v0.y + v0.z*v0.z + v0.w*v0.w
             + v1.x*v1.x + v1.y*v1.y + v1.z*v1.z + v1.w*v1.w;
#pragma unroll
    for (int off = 32; off; off >>= 1) { s += __shfl_xor(s, off); s2 += __shfl_xor(s2, off); }
    float mean = s * (1.f / 512.f);
    float var  = s2 * (1.f / 512.f) - mean * mean;
    float inv  = rsqrtf(var + 1e-5f);
    const float4* gp = (const float4*)g;
    const float4* bp = (const float4*)b;
    float4 g0 = gp[lane], g1 = gp[lane + 64], b0 = bp[lane], b1 = bp[lane + 64];
    US4 o0, o1;
    o0.a = f2bf((v0.x - mean) * inv * g0.x + b0.x);
    o0.b = f2bf((v0.y - mean) * inv * g0.y + b0.y);
    o0.c = f2bf((v0.z - mean) * inv * g0.z + b0.z);
    o0.d = f2bf((v0.w - mean) * inv * g0.w + b0.w);
    o1.a = f2bf((v1.x - mean) * inv * g1.x + b1.x);
    o1.b = f2bf((v1.y - mean) * inv * g1.y + b1.y);
    o1.c = f2bf((v1.z - mean) * inv * g1.z + b1.z);
    o1.d = f2bf((v1.w - mean) * inv * g1.w + b1.w);
    unsigned short* op = out + (size_t)tok * CCH;
    *(US4*)(op + 4 * lane)       = o0;
    *(US4*)(op + 256 + 4 * lane) = o1;
}

// ---------------- LayerNorm over C=512 (bf16 input), one wave per token, out bf16
__global__ __launch_bounds__(256) void ln_bf(const unsigned short* __restrict__ x,
                                             const float* __restrict__ g,
                                             const float* __restrict__ b,
                                             unsigned short* __restrict__ out, int ntok) {
    int lane = threadIdx.x & 63;
    int tok = blockIdx.x * 4 + (threadIdx.x >> 6);
    if (tok >= ntok) return;
    short8 v = *(const short8*)(x + (size_t)tok * CCH + lane * 8);
    float f[8];
#pragma unroll
    for (int j = 0; j < 8; ++j) f[j] = bf2f((unsigned short)v[j]);
    float s = 0.f, s2 = 0.f;
#pragma unroll
    for (int j = 0; j < 8; ++j) { s += f[j]; s2 += f[j] * f[j]; }
#pragma unroll
    for (int off = 32; off; off >>= 1) { s += __shfl_xor(s, off); s2 += __shfl_xor(s2, off); }
    float mean = s * (1.f / 512.f);
    float var  = s2 * (1.f / 512.f) - mean * mean;
    float inv  = rsqrtf(var + 1e-5f);
    const float4* gp = (const float4*)g + lane * 2;
    const float4* bp = (const float4*)b + lane * 2;
    float4 g0 = gp[0], g1 = gp[1], b0 = bp[0], b1 = bp[1];
    float gg[8] = {g0.x, g0.y, g0.z, g0.w, g1.x, g1.y, g1.z, g1.w};
    float bb[8] = {b0.x, b0.y, b0.z, b0.w, b1.x, b1.y, b1.z, b1.w};
    short8 o;
#pragma unroll
    for (int j = 0; j < 8; ++j) o[j] = (short)f2bf((f[j] - mean) * inv * gg[j] + bb[j]);
    *(short8*)(out + (size_t)tok * CCH + lane * 8) = o;
}

// ---------------- MFMA windowed attention: one wave per (window, head)
__global__ __launch_bounds__(256) void attn_mfma(const unsigned short* __restrict__ qkv,
                                                 const float* __restrict__ biasb,
                                                 unsigned short* __restrict__ o) {
    __shared__ __align__(16) unsigned short p_lds[4][48 * 64];
    __shared__ __align__(16) unsigned short v_lds[4][32 * 64];

    int tid  = threadIdx.x;
    int wv   = tid >> 6;
    int lane = tid & 63;
    int l15  = lane & 15;
    int g    = lane >> 4;

    int wid = blockIdx.x * 4 + wv;
    int h   = wid & 15;
    int win = wid >> 4;
    int img  = win >> 8;
    int wrow = (win >> 4) & 15;
    int wcol = win & 15;
    int tok_base = (img * 96 + wrow * 6) * 96 + wcol * 6;

    unsigned short* pw = p_lds[wv];
    unsigned short* vw = v_lds[wv];

    #define TOKOF(r) (tok_base + (r) + 90 * ((r) / 6))

    short8 z8 = {};
    for (int e = lane; e < 224; e += 64) {
        if (e < 128) {
            int ch = e >> 2, kst = 32 + (e & 3) * 8;
            *(short8*)(vw + ch * 64 + (kst ^ ((ch & 7) << 3))) = z8;
        } else {
            int ee = e - 128; int q = ee >> 1, kst = 48 + (ee & 1) * 8;
            *(short8*)(pw + q * 64 + (kst ^ ((q & 7) << 3))) = z8;
        }
    }

    for (int e = lane; e < 144; e += 64) {
        int r = e >> 2, c0 = (e & 3) * 8;
        short8 vv = *(const short8*)(qkv + (size_t)TOKOF(r) * 1536 + 1024 + h * 32 + c0);
#pragma unroll
        for (int j = 0; j < 8; ++j) {
            int ch = c0 + j;
            vw[ch * 64 + (r ^ ((ch & 7) << 3))] = (unsigned short)vv[j];
        }
    }

    short8 qf[3], kf[3];
#pragma unroll
    for (int t = 0; t < 3; ++t) {
        int r = t * 16 + l15;
        if (r < 36) {
            size_t ba = (size_t)TOKOF(r) * 1536 + h * 32 + g * 8;
            qf[t] = *(const short8*)(qkv + ba);
            kf[t] = *(const short8*)(qkv + ba + 512);
        } else { qf[t] = z8; kf[t] = z8; }
    }

    f32x4 s[3][3] = {};
#pragma unroll
    for (int mt = 0; mt < 3; ++mt)
#pragma unroll
        for (int nt = 0; nt < 3; ++nt)
            s[mt][nt] = __builtin_amdgcn_mfma_f32_16x16x32_bf16(qf[mt], kf[nt], s[mt][nt], 0, 0, 0);

    const float SCALE = 0.17677669529663687f;  // 1/sqrt(32)
    const float* bh = biasb + h * 2304;
#pragma unroll
    for (int mt = 0; mt < 3; ++mt) {
#pragma unroll
        for (int r = 0; r < 4; ++r) {
            int row = mt * 16 + g * 4 + r;
            const float* bb = bh + row * 48 + l15;
            float v0 = fmaf(s[mt][0][r], SCALE, bb[0]);
            float v1 = fmaf(s[mt][1][r], SCALE, bb[16]);
            float v2 = fmaf(s[mt][2][r], SCALE, bb[32]);
            float m = fmaxf(fmaxf(v0, v1), v2);
#pragma unroll
            for (int off = 1; off < 16; off <<= 1) m = fmaxf(m, __shfl_xor(m, off));
            float e0 = __expf(v0 - m), e1 = __expf(v1 - m), e2 = __expf(v2 - m);
            float sm = e0 + e1 + e2;
#pragma unroll
            for (int off = 1; off < 16; off <<= 1) sm += __shfl_xor(sm, off);
            float inv = 1.f / sm;
            int sw = (row & 7) << 3;
            unsigned short* pr = pw + row * 64;
            pr[(l15)      ^ sw] = f2bf(e0 * inv);
            pr[(16 + l15) ^ sw] = f2bf(e1 * inv);
            pr[(32 + l15) ^ sw] = f2bf(e2 * inv);
        }
    }

    f32x4 oacc[3][2] = {};
#pragma unroll
    for (int ks = 0; ks < 2; ++ks) {
        int kst = ks * 32 + g * 8;
        short8 bfr[2];
#pragma unroll
        for (int nt = 0; nt < 2; ++nt) {
            int c = nt * 16 + l15;
            bfr[nt] = *(const short8*)(vw + c * 64 + (kst ^ ((c & 7) << 3)));
        }
#pragma unroll
        for (int mt = 0; mt < 3; ++mt) {
            int q = mt * 16 + l15;
            short8 pa = *(const short8*)(pw + q * 64 + (kst ^ ((q & 7) << 3)));
#pragma unroll
            for (int nt = 0; nt < 2; ++nt)
                oacc[mt][nt] = __builtin_amdgcn_mfma_f32_16x16x32_bf16(pa, bfr[nt], oacc[mt][nt], 0, 0, 0);
        }
    }

#pragma unroll
    for (int mt = 0; mt < 3; ++mt) {
#pragma unroll
        for (int r = 0; r < 4; ++r) {
            int q = mt * 16 + g * 4 + r;
            if (q < 36) {
                size_t rb = (size_t)TOKOF(q) * 512 + h * 32;
#pragma unroll
                for (int nt = 0; nt < 2; ++nt)
                    o[rb + nt * 16 + l15] = f2bf(oacc[mt][nt][r]);
            }
        }
    }
    #undef TOKOF
}

// ---------------- 128x256-tile bf16 MFMA GEMM, 2 blocks/CU
// 512 thr = 8 waves (2M x 4N), per-wave 64x64 output (acc = 64 VGPR).
// LDS: ring-3 x 24KB (A 8KB + B 16KB) = 72KB -> two blocks co-resident/CU.
// Counted vmcnt 6/3/0; per K-tile(32): {stage t+2; vmcnt; bar; 8 ds_read;
//   lgkm(0); 16 MFMA; bar}. Pair-interleave XOR swizzle (R5-proven):
//   (row,granule g) -> line=row>>1, pos=(g+(row&1)*4)^(line&7), byte=line*128+pos*16
// EPI: 0 = bf16; 1 = bf16 + bias; 2 = bf16 gelu(x+bias); 3 = f32 (x+bias+resid_bf16)
template <int EPI>
__global__ __launch_bounds__(512, 4) void gemm8(const unsigned short* __restrict__ A,
                                                const unsigned short* __restrict__ Bt,
                                                int M, int N, int K,
                                                const float* __restrict__ bias,
                                                const unsigned short* __restrict__ resid,
                                                void* __restrict__ Cout) {
    extern __shared__ char lds[];
    int tid = threadIdx.x;
    int w = tid >> 6, lane = tid & 63;
    int l15 = lane & 15, grp = lane >> 4;
    int wm = w >> 2, wn = w & 3;            // 2M x 4N, wave tile 64x64

    int nbn = N >> 8;                        // N-tiles of 256
    int nwg = gridDim.x;
    int q = nwg >> 3, r = nwg & 7;
    int xcd = blockIdx.x & 7, pos_ = blockIdx.x >> 3;
    int wgid = (xcd < r ? xcd * (q + 1) : r * (q + 1) + (xcd - r) * q) + pos_;
    int bm = wgid / nbn, bn = wgid % nbn;    // bm over M/128

    int NT = K >> 5;

    // staging: dest linear tid*16; source inverse-swizzled
    int u = (tid & 7) ^ ((tid >> 3) & 7);
    int srow = ((tid >> 3) << 1) + (u >> 2);         // 0..127
    int scol = (u & 3) * 8;
    const unsigned short* aSrc = A  + ((size_t)bm * 128 + srow) * (size_t)K + scol;
    const unsigned short* bSrc = Bt + ((size_t)bn * 256 + srow) * (size_t)K + scol;

    #define STAGE(t) do { char* s_ = lds + ((t) % 3) * 24576; size_t ko_ = (size_t)(t) * 32; \
        gload16(aSrc + ko_,                   s_ + tid * 16); \
        gload16(bSrc + ko_,                   s_ + 8192  + tid * 16); \
        gload16(bSrc + ko_ + (size_t)128 * K, s_ + 16384 + tid * 16); } while (0)

    // fragment reads
    int rpos = (grp + (l15 & 1) * 4) ^ ((l15 >> 1) & 7);
    int aRd = (wm * 32 + (l15 >> 1)) * 128 + rpos * 16;            // + mi*1024
    int bRd = 8192 + (wn * 32 + (l15 >> 1)) * 128 + rpos * 16;     // + ni*1024

    f32x4 acc[4][4] = {};

    STAGE(0); STAGE(1);

    for (int t = 0; t < NT; ++t) {
        if (t + 2 < NT) {
            STAGE(t + 2);
            asm volatile("s_waitcnt vmcnt(6)" ::: "memory");   // tile t landed; t+1,t+2 fly
        } else if (t + 1 < NT) {
            asm volatile("s_waitcnt vmcnt(3)" ::: "memory");
        } else {
            asm volatile("s_waitcnt vmcnt(0)" ::: "memory");
        }
        __builtin_amdgcn_s_barrier();
        char* sb = lds + (t % 3) * 24576;
        short8 af[4], bf[4];
#pragma unroll
        for (int m = 0; m < 4; ++m) af[m] = *(const short8*)(sb + aRd + m * 1024);
#pragma unroll
        for (int n = 0; n < 4; ++n) bf[n] = *(const short8*)(sb + bRd + n * 1024);
        asm volatile("s_waitcnt lgkmcnt(0)" ::: "memory");
        __builtin_amdgcn_sched_barrier(0);
        __builtin_amdgcn_s_setprio(1);
#pragma unroll
        for (int m = 0; m < 4; ++m)
#pragma unroll
            for (int n = 0; n < 4; ++n)
                acc[m][n] = __builtin_amdgcn_mfma_f32_16x16x32_bf16(af[m], bf[n], acc[m][n], 0, 0, 0);
        __builtin_amdgcn_s_setprio(0);
        __builtin_amdgcn_s_barrier();        // all reads of slot t done -> restage safe
    }
    #undef STAGE

    // ---- epilogue (64 values/thread)
    int row0 = bm * 128 + wm * 64 + grp * 4;
    int col0 = bn * 256 + wn * 64 + l15;
#pragma unroll
    for (int m = 0; m < 4; ++m) {
#pragma unroll
        for (int n = 0; n < 4; ++n) {
            int col = col0 + n * 16;
            float bv = (EPI == 0) ? 0.f : bias[col];
#pragma unroll
            for (int r2 = 0; r2 < 4; ++r2) {
                int row = row0 + m * 16 + r2;
                size_t idx = (size_t)row * N + col;
                float val = acc[m][n][r2] + bv;
                if (EPI == 0) {
                    ((unsigned short*)Cout)[idx] = f2bf(val);
                } else if (EPI == 1) {
                    ((unsigned short*)Cout)[idx] = f2bf(val);
                } else if (EPI == 2) {
                    float u3 = val * val * val;
                    float z2 = 1.5957691216f * (val + 0.044715f * u3);
                    float e = __expf(z2);
                    float th = 1.f - 2.f / (e + 1.f);
                    float ge = 0.5f * val * (1.f + th);
                    ((unsigned short*)Cout)[idx] = f2bf(ge);
                } else {
                    ((float*)Cout)[idx] = val + bf2f(resid[idx]);
                }
            }
        }
    }
}

extern "C" void kernel_launch(void* const* d_in, const int* in_sizes, int n_in,
                              void* d_out, int out_size, void* d_ws, size_t ws_size,
                              hipStream_t stream) {
    const float* x       = (const float*)d_in[0];
    const float* w_qkv   = (const float*)d_in[1];
    const float* w_proj  = (const float*)d_in[2];
    const float* b_proj  = (const float*)d_in[3];
    const float* relb    = (const float*)d_in[4];
    const float* ln1g    = (const float*)d_in[5];
    const float* ln1b    = (const float*)d_in[6];
    const float* ln2g    = (const float*)d_in[7];
    const float* ln2b    = (const float*)d_in[8];
    const float* w_fc1   = (const float*)d_in[9];
    const float* b_fc1   = (const float*)d_in[10];
    const float* w_fc2   = (const float*)d_in[11];
    const float* b_fc2   = (const float*)d_in[12];
    float* out = (float*)d_out;

    hipFuncSetAttribute(reinterpret_cast<const void*>(&gemm8<0>),
                        hipFuncAttributeMaxDynamicSharedMemorySize, 73728);
    hipFuncSetAttribute(reinterpret_cast<const void*>(&gemm8<1>),
                        hipFuncAttributeMaxDynamicSharedMemorySize, 73728);
    hipFuncSetAttribute(reinterpret_cast<const void*>(&gemm8<2>),
                        hipFuncAttributeMaxDynamicSharedMemorySize, 73728);
    hipFuncSetAttribute(reinterpret_cast<const void*>(&gemm8<3>),
                        hipFuncAttributeMaxDynamicSharedMemorySize, 73728);

    char* w = (char*)d_ws;
    unsigned short* wT_qkv  = (unsigned short*)w; w += (size_t)1536 * 512 * 2;
    unsigned short* wT_proj = (unsigned short*)w; w += (size_t)512  * 512 * 2;
    unsigned short* wT_fc1  = (unsigned short*)w; w += (size_t)2048 * 512 * 2;
    unsigned short* wT_fc2  = (unsigned short*)w; w += (size_t)512  * 2048 * 2;
    float* biasb            = (float*)w;          w += (size_t)16 * 48 * 48 * 4;
    size_t wbytes = (size_t)(w - (char*)d_ws);

    // activation buffers: buf1 (512 bf16), buf2 (2048 bf16), buf3 (512 bf16, x2)
    int nchunk = 16;
    for (int c = 1; c <= 16; c *= 2) {
        size_t tokc = TOK / c;
        if (wbytes + tokc * 6144 <= ws_size) { nchunk = c; break; }
    }
    size_t tokc = TOK / nchunk;
    unsigned short* buf1 = (unsigned short*)w;
    unsigned short* buf2 = (unsigned short*)(w + tokc * 1024);
    unsigned short* buf3 = (unsigned short*)(w + tokc * 5120);

    wprep<<<(512 * 1536 + 255) / 256, 256, 0, stream>>>(w_qkv,  wT_qkv,  512, 1536);
    wprep<<<(512 * 512  + 255) / 256, 256, 0, stream>>>(w_proj, wT_proj, 512, 512);
    wprep<<<(512 * 2048 + 255) / 256, 256, 0, stream>>>(w_fc1,  wT_fc1,  512, 2048);
    wprep<<<(2048 * 512 + 255) / 256, 256, 0, stream>>>(w_fc2,  wT_fc2,  2048, 512);
    biasprep<<<(16 * 48 * 48 + 255) / 256, 256, 0, stream>>>(relb, biasb);

    int Mc = (int)tokc;
    int gm = Mc / 128;                 // M-tiles of 128 now
    int imgs = Mc / 9216;

    for (int c = 0; c < nchunk; ++c) {
        size_t toff = (size_t)c * tokc;
        const float* xc = x + toff * CCH;
        float* outc = out + toff * CCH;

        ln_k<<<Mc / 4, 256, 0, stream>>>(xc, ln1g, ln1b, buf1, Mc);
        gemm8<0><<<gm * 6, 512, 73728, stream>>>(buf1, wT_qkv, Mc, 1536, 512,
                                                 nullptr, nullptr, buf2);
        attn_mfma<<<imgs * 1024, 256, 0, stream>>>(buf2, biasb, buf1);
        gemm8<1><<<gm * 2, 512, 73728, stream>>>(buf1, wT_proj, Mc, 512, 512,
                                                 b_proj, nullptr, buf3);
        ln_bf<<<Mc / 4, 256, 0, stream>>>(buf3, ln2g, ln2b, buf1, Mc);
        gemm8<2><<<gm * 8, 512, 73728, stream>>>(buf1, wT_fc1, Mc, 2048, 512,
                                                 b_fc1, nullptr, buf2);
        gemm8<3><<<gm * 2, 512, 73728, stream>>>(buf2, wT_fc2, Mc, 512, 2048,
                                                 b_fc2, buf3, outc);
    }
}